// Round 13
// baseline (109.717 us; speedup 1.0000x reference)
//
#include <hip/hip_runtime.h>
#include <hip/hip_bf16.h>
#include <math.h>

// Dims: B=8, N=8, T=512, L=512, d=256, H=8, dk=32
typedef __attribute__((ext_vector_type(8))) short bf16x8;
typedef __attribute__((ext_vector_type(4))) short bf16x4;
typedef __attribute__((ext_vector_type(4))) float f32x4;

__device__ __forceinline__ short f2bf(float f) {
    return (short)__builtin_bit_cast(unsigned short, __float2bfloat16(f));
}
__device__ __forceinline__ float bf2f(short s) {
    return __builtin_bit_cast(float, ((unsigned)(unsigned short)s) << 16);
}
__device__ __forceinline__ unsigned pk2bf(float a, float b) {
    return ((unsigned)(unsigned short)f2bf(b) << 16) |
           (unsigned)(unsigned short)f2bf(a);
}

#if defined(__has_builtin)
#if __has_builtin(__builtin_amdgcn_mfma_f32_16x16x16bf16_1k)
#define HAVE_MFMA16 1
#endif
#endif

__device__ __forceinline__ f32x4 mfma16(bf16x4 a, bf16x4 b, f32x4 c) {
#ifdef HAVE_MFMA16
    return __builtin_amdgcn_mfma_f32_16x16x16bf16_1k(a, b, c, 0, 0, 0);
#else
    f32x4 d;
    asm volatile("v_mfma_f32_16x16x16_bf16 %0, %1, %2, %3"
                 : "=v"(d) : "v"(a), "v"(b), "v"(c));
    return d;
#endif
}

#define SCALE2 0.25503482403f   // (1/sqrt(32)) * log2(e)
#define CAP 272                  // K/V LDS chunk rows -> 39.1 KB = 4 blocks/CU
#define VS  (CAP + 14)           // Vt row stride = 286 shorts = 143 dwords (odd)

// ---------------- setup: weights->bf16 | W2/bias2/bkv | PE | pos scan | LN ----------------
__global__ __launch_bounds__(512) void setup_kernel(
    const float* __restrict__ Wq, const float* __restrict__ Wk,
    const float* __restrict__ Wv, const float* __restrict__ Wo,
    const float* __restrict__ Wts, const float* __restrict__ Waux,
    const float* __restrict__ bts, const float* __restrict__ baux,
    const float* __restrict__ bk, const float* __restrict__ bv,
    const float* __restrict__ x, const float* __restrict__ ln_a,
    const float* __restrict__ ln_b, const int* __restrict__ mask,
    short* __restrict__ wout, short* __restrict__ W2,
    float* __restrict__ bias2, float* __restrict__ bkv,
    float* __restrict__ pe, int* __restrict__ pos, int* __restrict__ cnt,
    short* __restrict__ xpe_bf, short* __restrict__ qin) {
    __shared__ float redA[8];
    __shared__ float redB[8];
    __shared__ int wsum[8];
    int bid = blockIdx.x, tid = threadIdx.x;
    if (bid < 128) {
        int i = bid * 512 + tid;
        wout[i]          = f2bf(Wq[i]);
        wout[65536 + i]  = f2bf(Wk[i]);
        wout[131072 + i] = f2bf(Wv[i]);
        wout[196608 + i] = f2bf(Wo[i]);
    } else if (bid < 176) {
        int idx = (bid - 128) * 512 + tid;   // 24576
        int e = idx / 96, ch = idx - e * 96;
        float v = 0.f;
        if (ch < 64) { if (e < 192) v = Wts[e * 64 + ch]; }
        else if (ch < 80) { if (e >= 192) v = Waux[(e - 192) * 16 + (ch - 64)]; }
        W2[idx] = f2bf(v);
        if (idx < 256) bias2[idx] = idx < 192 ? bts[idx] : baux[idx - 192];
        if (idx < 512) bkv[idx] = idx < 256 ? bk[idx] : bv[idx - 256];
    } else if (bid < 432) {
        int t = (bid - 176) * 2 + (tid >> 8);
        int dd = tid & 255;
        int i = dd >> 1;
        float div = expf((float)(2 * i) * (-9.210340371976184f / 256.0f));
        float ang = (float)t * div;
        pe[t * 256 + dd] = (dd & 1) ? cosf(ang) : sinf(ang);
    } else if (bid < 496) {
        int bn = bid - 432;
        int lane = tid & 63, wid = tid >> 6;
        int m = mask[bn * 512 + tid] != 0;
        int v = m;
#pragma unroll
        for (int off = 1; off < 64; off <<= 1) {
            int t = __shfl_up(v, off);
            if (lane >= off) v += t;
        }
        if (lane == 63) wsum[wid] = v;
        __syncthreads();
        int base = 0;
#pragma unroll
        for (int w = 0; w < 8; ++w) base += (w < wid) ? wsum[w] : 0;
        pos[bn * 512 + tid] = m ? (base + v - 1) : -1;
        if (tid == 511) cnt[bn] = base + v;
    } else {
        int half = tid >> 8;
        int d = tid & 255;
        int row = (bid - 496) * 2 + half;
        int t = row & 511;
        int i = d >> 1;
        float div = expf((float)(2 * i) * (-9.210340371976184f / 256.0f));
        float ang = (float)t * div;
        float pev = (d & 1) ? cosf(ang) : sinf(ang);
        float v = x[(size_t)row * 256 + d] + pev;
        xpe_bf[(size_t)row * 256 + d] = f2bf(v);
        float s = v;
#pragma unroll
        for (int off = 32; off > 0; off >>= 1) s += __shfl_xor(s, off);
        if ((tid & 63) == 0) redA[tid >> 6] = s;
        __syncthreads();
        int rb = half * 4;
        float mu = (redA[rb] + redA[rb + 1] + redA[rb + 2] + redA[rb + 3]) *
                   (1.0f / 256.0f);
        float dv = v - mu;
        float s2 = dv * dv;
#pragma unroll
        for (int off = 32; off > 0; off >>= 1) s2 += __shfl_xor(s2, off);
        if ((tid & 63) == 0) redB[tid >> 6] = s2;
        __syncthreads();
        float var = (redB[rb] + redB[rb + 1] + redB[rb + 2] + redB[rb + 3]) *
                    (1.0f / 255.0f);
        float sd = sqrtf(var);
        qin[(size_t)row * 256 + d] = f2bf(ln_a[d] * dv / (sd + 1e-6f) + ln_b[d]);
    }
}

// ---------------- kv embed as MFMA GEMM over K=96, scatter to compacted rows ----------------
__global__ __launch_bounds__(512, 2) void kv_gemm(
    const float* __restrict__ nbr_ts, const float* __restrict__ nbr_aux,
    const short* __restrict__ W2, const float* __restrict__ bias2,
    const float* __restrict__ pe, const int* __restrict__ pos,
    short* __restrict__ kvc) {
    __shared__ __align__(16) float S1[64 * 132];
    __shared__ __align__(16) float S2[16 * 132];
    __shared__ __align__(16) short A_lds[128 * 104];
    int tid = threadIdx.x;
    int bn = blockIdx.x, l0 = blockIdx.y * 128;
    const float* tsb = nbr_ts + (size_t)bn * 64 * 512;
    const float* axb = nbr_aux + (size_t)bn * 16 * 512;
#pragma unroll
    for (int it = 0; it < 4; ++it) {
        int idx = tid + it * 512;
        int cc = idx >> 5, lq = idx & 31;
        *(float4*)&S1[cc * 132 + lq * 4] =
            *(const float4*)&tsb[(size_t)cc * 512 + l0 + lq * 4];
    }
    {
        int cc = tid >> 5, lq = tid & 31;
        *(float4*)&S2[cc * 132 + lq * 4] =
            *(const float4*)&axb[(size_t)cc * 512 + l0 + lq * 4];
    }
    __syncthreads();
#pragma unroll
    for (int p = 0; p < 3; ++p) {
        int tk = tid + p * 512;
        int l = tk & 127, chunk = tk >> 7;
        union { bf16x8 v; unsigned u[4]; } v8;
        if (chunk < 8) {
#pragma unroll
            for (int i = 0; i < 4; ++i)
                v8.u[i] = pk2bf(S1[(chunk * 8 + 2 * i) * 132 + l],
                                S1[(chunk * 8 + 2 * i + 1) * 132 + l]);
        } else if (chunk < 10) {
#pragma unroll
            for (int i = 0; i < 4; ++i)
                v8.u[i] = pk2bf(S2[((chunk - 8) * 8 + 2 * i) * 132 + l],
                                S2[((chunk - 8) * 8 + 2 * i + 1) * 132 + l]);
        } else {
#pragma unroll
            for (int i = 0; i < 4; ++i) v8.u[i] = 0;
        }
        *(bf16x8*)&A_lds[l * 104 + chunk * 8] = v8.v;
    }
    __syncthreads();
    int wid = tid >> 6, lane = tid & 63;
    int g = lane >> 4, c = lane & 15;
    int lm = wid >> 2, le = wid & 3;
    bf16x8 wf[4][3];
#pragma unroll
    for (int nf = 0; nf < 4; ++nf)
#pragma unroll
        for (int ks = 0; ks < 3; ++ks)
            wf[nf][ks] = *(const bf16x8*)&W2[(size_t)(le * 64 + nf * 16 + c) * 96 +
                                             ks * 32 + g * 8];
    f32x4 acc[4][4];
#pragma unroll
    for (int i = 0; i < 4; ++i)
#pragma unroll
        for (int j = 0; j < 4; ++j) acc[i][j] = (f32x4){0.f, 0.f, 0.f, 0.f};
#pragma unroll
    for (int ks = 0; ks < 3; ++ks) {
#pragma unroll
        for (int mf = 0; mf < 4; ++mf) {
            bf16x8 af = *(const bf16x8*)&A_lds[(lm * 64 + mf * 16 + c) * 104 +
                                               ks * 32 + g * 8];
#pragma unroll
            for (int nf = 0; nf < 4; ++nf)
                acc[mf][nf] = __builtin_amdgcn_mfma_f32_16x16x32_bf16(
                    af, wf[nf][ks], acc[mf][nf], 0, 0, 0);
        }
    }
    float b2c[4];
#pragma unroll
    for (int nf = 0; nf < 4; ++nf) b2c[nf] = bias2[le * 64 + nf * 16 + c];
    short* kvb = kvc + (size_t)bn * 512 * 256;
    const int* posb = pos + bn * 512 + l0;
#pragma unroll
    for (int mf = 0; mf < 4; ++mf) {
#pragma unroll
        for (int r = 0; r < 4; ++r) {
            int lr = lm * 64 + mf * 16 + g * 4 + r;
            int p = posb[lr];
            if (p >= 0) {
#pragma unroll
                for (int nf = 0; nf < 4; ++nf) {
                    int e = le * 64 + nf * 16 + c;
                    kvb[(size_t)p * 256 + e] =
                        f2bf(acc[mf][nf][r] + b2c[nf] +
                             pe[(size_t)(l0 + lr) * 256 + e]);
                }
            }
        }
    }
}

// ---------------- merged q-projection + compact K|V projection ----------------
__global__ __launch_bounds__(256) void proj_gemm(
    const short* __restrict__ qin, const short* __restrict__ kvc,
    const short* __restrict__ wq, const short* __restrict__ wkv,
    const float* __restrict__ bq, const float* __restrict__ bkv,
    const int* __restrict__ cnt, short* __restrict__ qout,
    short* __restrict__ kv2) {
    int bx = blockIdx.x;
    const short* A; const short* Wm; const float* bias; short* C;
    int row0, col0, LDC; float esc;
    if (bx < 64) {
        row0 = (bx >> 1) * 128; col0 = (bx & 1) * 128;
        A = qin; Wm = wq; bias = bq; C = qout; LDC = 256; esc = SCALE2;
    } else {
        int idx = bx - 64;               // 1024 = bn(64) x mt(4) x ct(4)
        int bn = idx >> 4, mt = (idx >> 2) & 3, ct = idx & 3;
        int nvp = (cnt[bn] + 15) & ~15;
        row0 = mt * 128;
        if (row0 >= nvp) return;
        col0 = ct * 128;
        A = kvc + (size_t)bn * 512 * 256; Wm = wkv; bias = bkv;
        C = kv2 + (size_t)bn * 512 * 512; LDC = 512; esc = 1.0f;
    }
    __shared__ __align__(16) short As[128 * 40];
    __shared__ __align__(16) short Bs[128 * 40];
    int tid = threadIdx.x;
    int wid = tid >> 6, lane = tid & 63;
    int wm = wid >> 1, wn = wid & 1;
    int g = lane >> 4, c = lane & 15;
    f32x4 acc[4][4];
#pragma unroll
    for (int i = 0; i < 4; ++i)
#pragma unroll
        for (int j = 0; j < 4; ++j) acc[i][j] = (f32x4){0.f, 0.f, 0.f, 0.f};

    for (int k0 = 0; k0 < 256; k0 += 32) {
#pragma unroll
        for (int it = 0; it < 2; ++it) {
            int idx = tid + it * 256;
            int r = idx >> 2, ch = idx & 3;
            *(bf16x8*)&As[r * 40 + ch * 8] =
                *(const bf16x8*)&A[(size_t)(row0 + r) * 256 + k0 + ch * 8];
            *(bf16x8*)&Bs[r * 40 + ch * 8] =
                *(const bf16x8*)&Wm[(size_t)(col0 + r) * 256 + k0 + ch * 8];
        }
        __syncthreads();
        bf16x8 af[4], bfr[4];
#pragma unroll
        for (int mf = 0; mf < 4; ++mf)
            af[mf] = *(const bf16x8*)&As[(wm * 64 + mf * 16 + c) * 40 + g * 8];
#pragma unroll
        for (int nf = 0; nf < 4; ++nf)
            bfr[nf] = *(const bf16x8*)&Bs[(wn * 64 + nf * 16 + c) * 40 + g * 8];
#pragma unroll
        for (int mf = 0; mf < 4; ++mf)
#pragma unroll
            for (int nf = 0; nf < 4; ++nf)
                acc[mf][nf] = __builtin_amdgcn_mfma_f32_16x16x32_bf16(
                    af[mf], bfr[nf], acc[mf][nf], 0, 0, 0);
        __syncthreads();
    }
#pragma unroll
    for (int nf = 0; nf < 4; ++nf) {
        int col = col0 + wn * 64 + nf * 16 + c;
        float bz = bias[col];
#pragma unroll
        for (int mf = 0; mf < 4; ++mf)
#pragma unroll
            for (int r = 0; r < 4; ++r) {
                int row = row0 + wm * 64 + mf * 16 + g * 4 + r;
                C[(size_t)row * LDC + col] = f2bf((acc[mf][nf][r] + bz) * esc);
            }
    }
}

// ---------------- fused MFMA attention, compacted K/V, t-split 2-way ----------------
// grid 1024 = (bn, h, t-half). 8 waves; wave owns 32 t rows (2 t-frags).
template <bool MASKED>
__device__ __forceinline__ void attn_step(
    const short* K_lds, const short* Vt_lds, const bf16x8* qf,
    f32x4 (*ctxa)[2], f32x4* rsv, int l0, int clen, int g, int c) {
    bf16x8 ak = *(const bf16x8*)&K_lds[(l0 + c) * 40 + g * 8];
    bf16x4 vb0 = *(const bf16x4*)&Vt_lds[c * VS + l0 + g * 4];
    bf16x4 vb1 = *(const bf16x4*)&Vt_lds[(16 + c) * VS + l0 + g * 4];
    int lb = l0 + g * 4;
#pragma unroll
    for (int tf = 0; tf < 2; ++tf) {
        f32x4 s = __builtin_amdgcn_mfma_f32_16x16x32_bf16(
            ak, qf[tf], (f32x4){0.f, 0.f, 0.f, 0.f}, 0, 0, 0);
        float p0 = exp2f(s[0]);
        float p1 = exp2f(s[1]);
        float p2 = exp2f(s[2]);
        float p3 = exp2f(s[3]);
        if (MASKED) {
            p0 = (lb + 0 < clen) ? p0 : 0.f;
            p1 = (lb + 1 < clen) ? p1 : 0.f;
            p2 = (lb + 2 < clen) ? p2 : 0.f;
            p3 = (lb + 3 < clen) ? p3 : 0.f;
        }
        rsv[tf] += (f32x4){p0, p1, p2, p3};
        union { bf16x4 v; unsigned u[2]; } pu;
        pu.u[0] = pk2bf(p0, p1);
        pu.u[1] = pk2bf(p2, p3);
        __builtin_amdgcn_s_setprio(1);
        ctxa[tf][0] = mfma16(pu.v, vb0, ctxa[tf][0]);
        ctxa[tf][1] = mfma16(pu.v, vb1, ctxa[tf][1]);
        __builtin_amdgcn_s_setprio(0);
    }
}

__global__ __launch_bounds__(512, 8) void attn_kernel(
    const short* __restrict__ Q, const short* __restrict__ KV2,
    const int* __restrict__ cnt, short* __restrict__ ctx) {
    __shared__ __align__(16) short K_lds[CAP * 40];
    __shared__ __align__(16) short Vt_lds[32 * VS];
    int tid = threadIdx.x;
    int bx = blockIdx.x;
    int half = bx & 1, h = (bx >> 1) & 7, bn = bx >> 4, b = bn >> 3;
    int nv = cnt[bn];
    const short* kvr = KV2 + (size_t)bn * 512 * 512 + h * 32;

    int wid = tid >> 6, lane = tid & 63;
    int g = lane >> 4, c = lane & 15;
    int t0 = half * 256 + wid * 32;
    const short* qg = Q + ((size_t)b * 512 + t0 + c) * 256 + h * 32 + g * 8;
    bf16x8 qf[2];
#pragma unroll
    for (int tf = 0; tf < 2; ++tf)
        qf[tf] = *(const bf16x8*)&qg[(size_t)tf * 16 * 256];

    f32x4 ctxa[2][2];
    f32x4 rsv[2];
#pragma unroll
    for (int tf = 0; tf < 2; ++tf) {
        ctxa[tf][0] = (f32x4){0.f, 0.f, 0.f, 0.f};
        ctxa[tf][1] = (f32x4){0.f, 0.f, 0.f, 0.f};
        rsv[tf] = (f32x4){0.f, 0.f, 0.f, 0.f};
    }

    for (int base = 0; base < nv; base += CAP) {
        int rem = nv - base;
        int clen = rem < CAP ? rem : CAP;
        int clenp = (clen + 15) & ~15;
        if (base) __syncthreads();   // prior chunk fully consumed
        for (int idx = tid; idx < clenp * 4; idx += 512) {
            int i = idx >> 2, ch = idx & 3;
            bf16x8 kval = (bf16x8){0, 0, 0, 0, 0, 0, 0, 0};
            bf16x8 vval = (bf16x8){0, 0, 0, 0, 0, 0, 0, 0};
            if (i < clen) {
                size_t ro = (size_t)(base + i) * 512;
                kval = *(const bf16x8*)&kvr[ro + ch * 8];
                vval = *(const bf16x8*)&kvr[ro + 256 + ch * 8];
            }
            *(bf16x8*)&K_lds[i * 40 + ch * 8] = kval;
#pragma unroll
            for (int k = 0; k < 8; ++k)
                Vt_lds[(ch * 8 + k) * VS + i] = vval[k];
        }
        __syncthreads();
        int nfull = clen & ~15;
        for (int l0 = 0; l0 < nfull; l0 += 16)
            attn_step<false>(K_lds, Vt_lds, qf, ctxa, rsv, l0, clen, g, c);
        if (nfull < clenp)
            attn_step<true>(K_lds, Vt_lds, qf, ctxa, rsv, nfull, clen, g, c);
    }
#ifndef HAVE_MFMA16
    asm volatile("s_nop 7\ns_nop 7");
#endif
#pragma unroll
    for (int tf = 0; tf < 2; ++tf) {
        float r = (rsv[tf][0] + rsv[tf][1]) + (rsv[tf][2] + rsv[tf][3]);
        r += __shfl_xor(r, 16);
        r += __shfl_xor(r, 32);
        float inv = 1.f / r;   // rowsum for t-row = c, replicated over groups
#pragma unroll
        for (int rr = 0; rr < 4; ++rr) {
            float invr = __shfl(inv, (lane & 48) | (g * 4 + rr));
            ctxa[tf][0][rr] *= invr;
            ctxa[tf][1][rr] *= invr;
        }
    }
    __syncthreads();   // all waves done with K_lds/Vt_lds; reuse K_lds as staging
    // single-pass ctx write-back: 256 local rows via K_lds[0..256)
    int tl = wid * 32;
#pragma unroll
    for (int tf = 0; tf < 2; ++tf)
#pragma unroll
        for (int df = 0; df < 2; ++df)
#pragma unroll
            for (int rr = 0; rr < 4; ++rr)
                K_lds[(tl + tf * 16 + g * 4 + rr) * 40 + df * 16 + c] =
                    f2bf(ctxa[tf][df][rr]);
    __syncthreads();
    short* cg = ctx + (size_t)bn * 512 * 256 + h * 32 +
                (size_t)half * 256 * 256;
#pragma unroll
    for (int it = 0; it < 2; ++it) {
        int idx = tid + it * 512;
        int l = idx >> 2, ch = idx & 3;
        *(bf16x8*)&cg[(size_t)l * 256 + ch * 8] =
            *(const bf16x8*)&K_lds[l * 40 + ch * 8];
    }
}

// ---------------- fused Wo-GEMM + edge + mean_n (T14 async-STAGE split) ----------------
__global__ __launch_bounds__(256, 3) void wo_final(
    const short* __restrict__ ctx, const short* __restrict__ wo,
    const float* __restrict__ bo, const short* __restrict__ xpe,
    const float* __restrict__ nbr_edge, const float* __restrict__ Wedge,
    const float* __restrict__ bedge, float* __restrict__ out) {
    __shared__ __align__(16) short Ws[64 * 264];
    __shared__ __align__(16) short As[32 * 264];
    __shared__ __align__(16) float edge_s[8][36];
    int bx = blockIdx.x;
    int b = bx >> 6, tt = (bx >> 2) & 15, dt = bx & 3;
    int t0 = tt * 32, d0 = dt * 64;
    int tid = threadIdx.x;
    int wid = tid >> 6, lane = tid & 63;
    int th = wid & 1, dh = wid >> 1;
    int g = lane >> 4, c = lane & 15;

#pragma unroll
    for (int it = 0; it < 8; ++it) {
        int idx = tid + it * 256;
        int r = idx >> 5, kk = (idx & 31) * 8;
        *(bf16x8*)&Ws[r * 264 + kk] =
            *(const bf16x8*)&wo[(size_t)(d0 + r) * 256 + kk];
    }
    int trloc = th * 16 + g * 4;
    int dcol[2];
    float we[2][8], be[2], xb[2][4];
#pragma unroll
    for (int j = 0; j < 2; ++j) {
        dcol[j] = d0 + dh * 32 + j * 16 + c;
#pragma unroll
        for (int cc = 0; cc < 8; ++cc) we[j][cc] = Wedge[dcol[j] * 8 + cc];
        be[j] = bedge[dcol[j]];
        float boj = bo[dcol[j]];
#pragma unroll
        for (int r = 0; r < 4; ++r)
            xb[j][r] = bf2f(xpe[((size_t)b * 512 + t0 + trloc + r) * 256 +
                                dcol[j]]) + boj;
    }
    f32x4 oacc[2] = {(f32x4){0.f, 0.f, 0.f, 0.f}, (f32x4){0.f, 0.f, 0.f, 0.f}};

    int sr = tid >> 5, skk = (tid & 31) * 8;   // staging coords (4 rows/thread)
    int ec = tid >> 5, etl = tid & 31;         // edge coords
    // prologue: load n=0 into regs
    bf16x8 rv[4];
    float ev;
    {
        int bn = b * 8;
#pragma unroll
        for (int it = 0; it < 4; ++it)
            rv[it] = *(const bf16x8*)&ctx[((size_t)bn * 512 + t0 + sr + it * 8) *
                                          256 + skk];
        ev = nbr_edge[((size_t)bn * 8 + ec) * 512 + t0 + etl];
    }

    for (int n = 0; n < 8; ++n) {
        // write staged regs for this n
#pragma unroll
        for (int it = 0; it < 4; ++it)
            *(bf16x8*)&As[(sr + it * 8) * 264 + skk] = rv[it];
        edge_s[ec][etl] = ev;
        __syncthreads();
        // issue next n's loads (latency hides under MFMA below)
        if (n < 7) {
            int bn = b * 8 + n + 1;
#pragma unroll
            for (int it = 0; it < 4; ++it)
                rv[it] = *(const bf16x8*)&ctx[((size_t)bn * 512 + t0 + sr +
                                              it * 8) * 256 + skk];
            ev = nbr_edge[((size_t)bn * 8 + ec) * 512 + t0 + etl];
        }
        f32x4 acc[2] = {(f32x4){0.f, 0.f, 0.f, 0.f},
                        (f32x4){0.f, 0.f, 0.f, 0.f}};
#pragma unroll
        for (int k0 = 0; k0 < 8; ++k0) {
            bf16x8 af = *(const bf16x8*)&As[(th * 16 + c) * 264 + k0 * 32 + g * 8];
#pragma unroll
            for (int j = 0; j < 2; ++j) {
                bf16x8 bf = *(const bf16x8*)&Ws[(dh * 32 + j * 16 + c) * 264 +
                                                k0 * 32 + g * 8];
                acc[j] = __builtin_amdgcn_mfma_f32_16x16x32_bf16(af, bf, acc[j],
                                                                 0, 0, 0);
            }
        }
#pragma unroll
        for (int j = 0; j < 2; ++j)
#pragma unroll
            for (int r = 0; r < 4; ++r) {
                float e = be[j];
#pragma unroll
                for (int cc = 0; cc < 8; ++cc)
                    e = fmaf(edge_s[cc][trloc + r], we[j][cc], e);
                oacc[j][r] = fmaf(acc[j][r] + xb[j][r], e, oacc[j][r]);
            }
        __syncthreads();   // all reads of As/edge_s done before next write
    }
#pragma unroll
    for (int j = 0; j < 2; ++j)
#pragma unroll
        for (int r = 0; r < 4; ++r)
            out[((size_t)b * 512 + t0 + trloc + r) * 256 + dcol[j]] =
                oacc[j][r] * 0.125f;
}

extern "C" void kernel_launch(void* const* d_in, const int* in_sizes, int n_in,
                              void* d_out, int out_size, void* d_ws, size_t ws_size,
                              hipStream_t stream) {
    const float* x        = (const float*)d_in[0];
    const float* nbr_ts   = (const float*)d_in[1];
    const float* nbr_aux  = (const float*)d_in[2];
    const float* nbr_edge = (const float*)d_in[3];
    const int*   mask     = (const int*)d_in[4];
    const float* Wts  = (const float*)d_in[5];
    const float* bts  = (const float*)d_in[6];
    const float* Waux = (const float*)d_in[7];
    const float* baux = (const float*)d_in[8];
    const float* Wedge= (const float*)d_in[9];
    const float* bedge= (const float*)d_in[10];
    const float* ln_a = (const float*)d_in[11];
    const float* ln_b = (const float*)d_in[12];
    const float* Wq = (const float*)d_in[13];
    const float* bq = (const float*)d_in[14];
    const float* Wk = (const float*)d_in[15];
    const float* bk = (const float*)d_in[16];
    const float* Wv = (const float*)d_in[17];
    const float* bv = (const float*)d_in[18];
    const float* Wo = (const float*)d_in[19];
    const float* bo = (const float*)d_in[20];
    float* out = (float*)d_out;

    char* W = (char*)d_ws;
    float* pe_f    = (float*)(W);                 // 512 KB
    short* xpe_bf  = (short*)(W + 524288);        // 2 MB
    short* qin_bf  = (short*)(W + 4718592);       // 2 MB
    short* q_bf    = (short*)(W + 6815744);       // 2 MB
    short* kvc_bf  = (short*)(W + 8912896);       // 16 MB (compacted kv embed)
    short* kv2c_bf = (short*)(W + 25690112);      // 32 MB (compacted K|V, LDC 512)
    short* ctx_bf  = (short*)(W + 59244544);      // 16 MB
    short* w_bf    = (short*)(W + 92798976);      // 512 KB
    short* W2_bf   = (short*)(W + 93323264);      // 48 KB
    float* bias2_f = (float*)(W + 93372416);      // 1 KB
    float* bkv_f   = (float*)(W + 93373440);      // 2 KB
    int*   pos     = (int*)  (W + 93375488);      // 128 KB
    int*   cnt     = (int*)  (W + 93506560);      // 256 B
    short* wq_bf = w_bf;
    short* wkv_bf = w_bf + 65536;  // wk,wv contiguous => one [512][256] matrix
    short* wo_bf = w_bf + 196608;

    setup_kernel<<<2544, 512, 0, stream>>>(
        Wq, Wk, Wv, Wo, Wts, Waux, bts, baux, bk, bv, x, ln_a, ln_b, mask,
        w_bf, W2_bf, bias2_f, bkv_f, pe_f, pos, cnt, xpe_bf, qin_bf);
    kv_gemm<<<dim3(64, 4), 512, 0, stream>>>(nbr_ts, nbr_aux, W2_bf, bias2_f,
                                             pe_f, pos, kvc_bf);
    proj_gemm<<<1088, 256, 0, stream>>>(qin_bf, kvc_bf, wq_bf, wkv_bf, bq,
                                        bkv_f, cnt, q_bf, kv2c_bf);
    attn_kernel<<<1024, 512, 0, stream>>>(q_bf, kv2c_bf, cnt, ctx_bf);
    wo_final<<<512, 256, 0, stream>>>(ctx_bf, wo_bf, bo, xpe_bf, nbr_edge,
                                      Wedge, bedge, out);
}

// Round 14
// 102.756 us; speedup vs baseline: 1.0677x; 1.0677x over previous
//
#include <hip/hip_runtime.h>
#include <hip/hip_bf16.h>
#include <math.h>

// Dims: B=8, N=8, T=512, L=512, d=256, H=8, dk=32
typedef __attribute__((ext_vector_type(8))) short bf16x8;
typedef __attribute__((ext_vector_type(4))) short bf16x4;
typedef __attribute__((ext_vector_type(4))) float f32x4;

__device__ __forceinline__ short f2bf(float f) {
    return (short)__builtin_bit_cast(unsigned short, __float2bfloat16(f));
}
__device__ __forceinline__ float bf2f(short s) {
    return __builtin_bit_cast(float, ((unsigned)(unsigned short)s) << 16);
}
__device__ __forceinline__ unsigned pk2bf(float a, float b) {
    return ((unsigned)(unsigned short)f2bf(b) << 16) |
           (unsigned)(unsigned short)f2bf(a);
}

#if defined(__has_builtin)
#if __has_builtin(__builtin_amdgcn_mfma_f32_16x16x16bf16_1k)
#define HAVE_MFMA16 1
#endif
#endif

__device__ __forceinline__ f32x4 mfma16(bf16x4 a, bf16x4 b, f32x4 c) {
#ifdef HAVE_MFMA16
    return __builtin_amdgcn_mfma_f32_16x16x16bf16_1k(a, b, c, 0, 0, 0);
#else
    f32x4 d;
    asm volatile("v_mfma_f32_16x16x16_bf16 %0, %1, %2, %3"
                 : "=v"(d) : "v"(a), "v"(b), "v"(c));
    return d;
#endif
}

#define SCALE2 0.25503482403f   // (1/sqrt(32)) * log2(e)
#define CAP 272                  // K/V LDS chunk rows -> 39.9 KB = 4 blocks/CU
#define VS  (CAP + 12)           // Vt row stride 284 shorts: c*VS*2 % 8 == 0 (b64-aligned)

// ---------------- setup: weights->bf16 | W2/bias2/bkv | PE | pos scan | LN ----------------
__global__ __launch_bounds__(512) void setup_kernel(
    const float* __restrict__ Wq, const float* __restrict__ Wk,
    const float* __restrict__ Wv, const float* __restrict__ Wo,
    const float* __restrict__ Wts, const float* __restrict__ Waux,
    const float* __restrict__ bts, const float* __restrict__ baux,
    const float* __restrict__ bk, const float* __restrict__ bv,
    const float* __restrict__ x, const float* __restrict__ ln_a,
    const float* __restrict__ ln_b, const int* __restrict__ mask,
    short* __restrict__ wout, short* __restrict__ W2,
    float* __restrict__ bias2, float* __restrict__ bkv,
    float* __restrict__ pe, int* __restrict__ pos, int* __restrict__ cnt,
    short* __restrict__ xpe_bf, short* __restrict__ qin) {
    __shared__ float redA[8];
    __shared__ float redB[8];
    __shared__ int wsum[8];
    int bid = blockIdx.x, tid = threadIdx.x;
    if (bid < 128) {
        int i = bid * 512 + tid;
        wout[i]          = f2bf(Wq[i]);
        wout[65536 + i]  = f2bf(Wk[i]);
        wout[131072 + i] = f2bf(Wv[i]);
        wout[196608 + i] = f2bf(Wo[i]);
    } else if (bid < 176) {
        int idx = (bid - 128) * 512 + tid;   // 24576
        int e = idx / 96, ch = idx - e * 96;
        float v = 0.f;
        if (ch < 64) { if (e < 192) v = Wts[e * 64 + ch]; }
        else if (ch < 80) { if (e >= 192) v = Waux[(e - 192) * 16 + (ch - 64)]; }
        W2[idx] = f2bf(v);
        if (idx < 256) bias2[idx] = idx < 192 ? bts[idx] : baux[idx - 192];
        if (idx < 512) bkv[idx] = idx < 256 ? bk[idx] : bv[idx - 256];
    } else if (bid < 432) {
        int t = (bid - 176) * 2 + (tid >> 8);
        int dd = tid & 255;
        int i = dd >> 1;
        float div = expf((float)(2 * i) * (-9.210340371976184f / 256.0f));
        float ang = (float)t * div;
        pe[t * 256 + dd] = (dd & 1) ? cosf(ang) : sinf(ang);
    } else if (bid < 496) {
        int bn = bid - 432;
        int lane = tid & 63, wid = tid >> 6;
        int m = mask[bn * 512 + tid] != 0;
        int v = m;
#pragma unroll
        for (int off = 1; off < 64; off <<= 1) {
            int t = __shfl_up(v, off);
            if (lane >= off) v += t;
        }
        if (lane == 63) wsum[wid] = v;
        __syncthreads();
        int base = 0;
#pragma unroll
        for (int w = 0; w < 8; ++w) base += (w < wid) ? wsum[w] : 0;
        pos[bn * 512 + tid] = m ? (base + v - 1) : -1;
        if (tid == 511) cnt[bn] = base + v;
    } else {
        int half = tid >> 8;
        int d = tid & 255;
        int row = (bid - 496) * 2 + half;
        int t = row & 511;
        int i = d >> 1;
        float div = expf((float)(2 * i) * (-9.210340371976184f / 256.0f));
        float ang = (float)t * div;
        float pev = (d & 1) ? cosf(ang) : sinf(ang);
        float v = x[(size_t)row * 256 + d] + pev;
        xpe_bf[(size_t)row * 256 + d] = f2bf(v);
        float s = v;
#pragma unroll
        for (int off = 32; off > 0; off >>= 1) s += __shfl_xor(s, off);
        if ((tid & 63) == 0) redA[tid >> 6] = s;
        __syncthreads();
        int rb = half * 4;
        float mu = (redA[rb] + redA[rb + 1] + redA[rb + 2] + redA[rb + 3]) *
                   (1.0f / 256.0f);
        float dv = v - mu;
        float s2 = dv * dv;
#pragma unroll
        for (int off = 32; off > 0; off >>= 1) s2 += __shfl_xor(s2, off);
        if ((tid & 63) == 0) redB[tid >> 6] = s2;
        __syncthreads();
        float var = (redB[rb] + redB[rb + 1] + redB[rb + 2] + redB[rb + 3]) *
                    (1.0f / 255.0f);
        float sd = sqrtf(var);
        qin[(size_t)row * 256 + d] = f2bf(ln_a[d] * dv / (sd + 1e-6f) + ln_b[d]);
    }
}

// ---------------- kv embed as MFMA GEMM over K=96, scatter to compacted rows ----------------
__global__ __launch_bounds__(512, 2) void kv_gemm(
    const float* __restrict__ nbr_ts, const float* __restrict__ nbr_aux,
    const short* __restrict__ W2, const float* __restrict__ bias2,
    const float* __restrict__ pe, const int* __restrict__ pos,
    short* __restrict__ kvc) {
    __shared__ __align__(16) float S1[64 * 132];
    __shared__ __align__(16) float S2[16 * 132];
    __shared__ __align__(16) short A_lds[128 * 104];
    int tid = threadIdx.x;
    int bn = blockIdx.x, l0 = blockIdx.y * 128;
    const float* tsb = nbr_ts + (size_t)bn * 64 * 512;
    const float* axb = nbr_aux + (size_t)bn * 16 * 512;
#pragma unroll
    for (int it = 0; it < 4; ++it) {
        int idx = tid + it * 512;
        int cc = idx >> 5, lq = idx & 31;
        *(float4*)&S1[cc * 132 + lq * 4] =
            *(const float4*)&tsb[(size_t)cc * 512 + l0 + lq * 4];
    }
    {
        int cc = tid >> 5, lq = tid & 31;
        *(float4*)&S2[cc * 132 + lq * 4] =
            *(const float4*)&axb[(size_t)cc * 512 + l0 + lq * 4];
    }
    __syncthreads();
#pragma unroll
    for (int p = 0; p < 3; ++p) {
        int tk = tid + p * 512;
        int l = tk & 127, chunk = tk >> 7;
        union { bf16x8 v; unsigned u[4]; } v8;
        if (chunk < 8) {
#pragma unroll
            for (int i = 0; i < 4; ++i)
                v8.u[i] = pk2bf(S1[(chunk * 8 + 2 * i) * 132 + l],
                                S1[(chunk * 8 + 2 * i + 1) * 132 + l]);
        } else if (chunk < 10) {
#pragma unroll
            for (int i = 0; i < 4; ++i)
                v8.u[i] = pk2bf(S2[((chunk - 8) * 8 + 2 * i) * 132 + l],
                                S2[((chunk - 8) * 8 + 2 * i + 1) * 132 + l]);
        } else {
#pragma unroll
            for (int i = 0; i < 4; ++i) v8.u[i] = 0;
        }
        *(bf16x8*)&A_lds[l * 104 + chunk * 8] = v8.v;
    }
    __syncthreads();
    int wid = tid >> 6, lane = tid & 63;
    int g = lane >> 4, c = lane & 15;
    int lm = wid >> 2, le = wid & 3;
    bf16x8 wf[4][3];
#pragma unroll
    for (int nf = 0; nf < 4; ++nf)
#pragma unroll
        for (int ks = 0; ks < 3; ++ks)
            wf[nf][ks] = *(const bf16x8*)&W2[(size_t)(le * 64 + nf * 16 + c) * 96 +
                                             ks * 32 + g * 8];
    f32x4 acc[4][4];
#pragma unroll
    for (int i = 0; i < 4; ++i)
#pragma unroll
        for (int j = 0; j < 4; ++j) acc[i][j] = (f32x4){0.f, 0.f, 0.f, 0.f};
#pragma unroll
    for (int ks = 0; ks < 3; ++ks) {
#pragma unroll
        for (int mf = 0; mf < 4; ++mf) {
            bf16x8 af = *(const bf16x8*)&A_lds[(lm * 64 + mf * 16 + c) * 104 +
                                               ks * 32 + g * 8];
#pragma unroll
            for (int nf = 0; nf < 4; ++nf)
                acc[mf][nf] = __builtin_amdgcn_mfma_f32_16x16x32_bf16(
                    af, wf[nf][ks], acc[mf][nf], 0, 0, 0);
        }
    }
    float b2c[4];
#pragma unroll
    for (int nf = 0; nf < 4; ++nf) b2c[nf] = bias2[le * 64 + nf * 16 + c];
    short* kvb = kvc + (size_t)bn * 512 * 256;
    const int* posb = pos + bn * 512 + l0;
#pragma unroll
    for (int mf = 0; mf < 4; ++mf) {
#pragma unroll
        for (int r = 0; r < 4; ++r) {
            int lr = lm * 64 + mf * 16 + g * 4 + r;
            int p = posb[lr];
            if (p >= 0) {
#pragma unroll
                for (int nf = 0; nf < 4; ++nf) {
                    int e = le * 64 + nf * 16 + c;
                    kvb[(size_t)p * 256 + e] =
                        f2bf(acc[mf][nf][r] + b2c[nf] +
                             pe[(size_t)(l0 + lr) * 256 + e]);
                }
            }
        }
    }
}

// ---------------- merged q-projection + compact K|V projection ----------------
__global__ __launch_bounds__(256) void proj_gemm(
    const short* __restrict__ qin, const short* __restrict__ kvc,
    const short* __restrict__ wq, const short* __restrict__ wkv,
    const float* __restrict__ bq, const float* __restrict__ bkv,
    const int* __restrict__ cnt, short* __restrict__ qout,
    short* __restrict__ kv2) {
    int bx = blockIdx.x;
    const short* A; const short* Wm; const float* bias; short* C;
    int row0, col0, LDC; float esc;
    if (bx < 64) {
        row0 = (bx >> 1) * 128; col0 = (bx & 1) * 128;
        A = qin; Wm = wq; bias = bq; C = qout; LDC = 256; esc = SCALE2;
    } else {
        int idx = bx - 64;               // 1024 = bn(64) x mt(4) x ct(4)
        int bn = idx >> 4, mt = (idx >> 2) & 3, ct = idx & 3;
        int nvp = (cnt[bn] + 15) & ~15;
        row0 = mt * 128;
        if (row0 >= nvp) return;
        col0 = ct * 128;
        A = kvc + (size_t)bn * 512 * 256; Wm = wkv; bias = bkv;
        C = kv2 + (size_t)bn * 512 * 512; LDC = 512; esc = 1.0f;
    }
    __shared__ __align__(16) short As[128 * 40];
    __shared__ __align__(16) short Bs[128 * 40];
    int tid = threadIdx.x;
    int wid = tid >> 6, lane = tid & 63;
    int wm = wid >> 1, wn = wid & 1;
    int g = lane >> 4, c = lane & 15;
    f32x4 acc[4][4];
#pragma unroll
    for (int i = 0; i < 4; ++i)
#pragma unroll
        for (int j = 0; j < 4; ++j) acc[i][j] = (f32x4){0.f, 0.f, 0.f, 0.f};

    for (int k0 = 0; k0 < 256; k0 += 32) {
#pragma unroll
        for (int it = 0; it < 2; ++it) {
            int idx = tid + it * 256;
            int r = idx >> 2, ch = idx & 3;
            *(bf16x8*)&As[r * 40 + ch * 8] =
                *(const bf16x8*)&A[(size_t)(row0 + r) * 256 + k0 + ch * 8];
            *(bf16x8*)&Bs[r * 40 + ch * 8] =
                *(const bf16x8*)&Wm[(size_t)(col0 + r) * 256 + k0 + ch * 8];
        }
        __syncthreads();
        bf16x8 af[4], bfr[4];
#pragma unroll
        for (int mf = 0; mf < 4; ++mf)
            af[mf] = *(const bf16x8*)&As[(wm * 64 + mf * 16 + c) * 40 + g * 8];
#pragma unroll
        for (int nf = 0; nf < 4; ++nf)
            bfr[nf] = *(const bf16x8*)&Bs[(wn * 64 + nf * 16 + c) * 40 + g * 8];
#pragma unroll
        for (int mf = 0; mf < 4; ++mf)
#pragma unroll
            for (int nf = 0; nf < 4; ++nf)
                acc[mf][nf] = __builtin_amdgcn_mfma_f32_16x16x32_bf16(
                    af[mf], bfr[nf], acc[mf][nf], 0, 0, 0);
        __syncthreads();
    }
#pragma unroll
    for (int nf = 0; nf < 4; ++nf) {
        int col = col0 + wn * 64 + nf * 16 + c;
        float bz = bias[col];
#pragma unroll
        for (int mf = 0; mf < 4; ++mf)
#pragma unroll
            for (int r = 0; r < 4; ++r) {
                int row = row0 + wm * 64 + mf * 16 + g * 4 + r;
                C[(size_t)row * LDC + col] = f2bf((acc[mf][nf][r] + bz) * esc);
            }
    }
}

// ---------------- fused MFMA attention, compacted K/V, t-split 2-way ----------------
// grid 1024 = (bn, h, t-half). 8 waves; wave owns 32 t rows (2 t-frags).
// CAP=272 -> LDS 39.9KB -> 4 blocks/CU resident = exactly one full round.
template <bool MASKED>
__device__ __forceinline__ void attn_step(
    const short* K_lds, const short* Vt_lds, const bf16x8* qf,
    f32x4 (*ctxa)[2], f32x4* rsv, int l0, int clen, int g, int c) {
    bf16x8 ak = *(const bf16x8*)&K_lds[(l0 + c) * 40 + g * 8];
    bf16x4 vb0 = *(const bf16x4*)&Vt_lds[c * VS + l0 + g * 4];
    bf16x4 vb1 = *(const bf16x4*)&Vt_lds[(16 + c) * VS + l0 + g * 4];
    int lb = l0 + g * 4;
#pragma unroll
    for (int tf = 0; tf < 2; ++tf) {
        f32x4 s = __builtin_amdgcn_mfma_f32_16x16x32_bf16(
            ak, qf[tf], (f32x4){0.f, 0.f, 0.f, 0.f}, 0, 0, 0);
        float p0 = exp2f(s[0]);
        float p1 = exp2f(s[1]);
        float p2 = exp2f(s[2]);
        float p3 = exp2f(s[3]);
        if (MASKED) {
            p0 = (lb + 0 < clen) ? p0 : 0.f;
            p1 = (lb + 1 < clen) ? p1 : 0.f;
            p2 = (lb + 2 < clen) ? p2 : 0.f;
            p3 = (lb + 3 < clen) ? p3 : 0.f;
        }
        rsv[tf] += (f32x4){p0, p1, p2, p3};
        union { bf16x4 v; unsigned u[2]; } pu;
        pu.u[0] = pk2bf(p0, p1);
        pu.u[1] = pk2bf(p2, p3);
        __builtin_amdgcn_s_setprio(1);
        ctxa[tf][0] = mfma16(pu.v, vb0, ctxa[tf][0]);
        ctxa[tf][1] = mfma16(pu.v, vb1, ctxa[tf][1]);
        __builtin_amdgcn_s_setprio(0);
    }
}

__global__ __launch_bounds__(512, 8) void attn_kernel(
    const short* __restrict__ Q, const short* __restrict__ KV2,
    const int* __restrict__ cnt, short* __restrict__ ctx) {
    __shared__ __align__(16) short K_lds[CAP * 40];
    __shared__ __align__(16) short Vt_lds[32 * VS];
    int tid = threadIdx.x;
    int bx = blockIdx.x;
    int half = bx & 1, h = (bx >> 1) & 7, bn = bx >> 4, b = bn >> 3;
    int nv = cnt[bn];
    const short* kvr = KV2 + (size_t)bn * 512 * 512 + h * 32;

    int wid = tid >> 6, lane = tid & 63;
    int g = lane >> 4, c = lane & 15;
    int t0 = half * 256 + wid * 32;
    const short* qg = Q + ((size_t)b * 512 + t0 + c) * 256 + h * 32 + g * 8;
    bf16x8 qf[2];
#pragma unroll
    for (int tf = 0; tf < 2; ++tf)
        qf[tf] = *(const bf16x8*)&qg[(size_t)tf * 16 * 256];

    f32x4 ctxa[2][2];
    f32x4 rsv[2];
#pragma unroll
    for (int tf = 0; tf < 2; ++tf) {
        ctxa[tf][0] = (f32x4){0.f, 0.f, 0.f, 0.f};
        ctxa[tf][1] = (f32x4){0.f, 0.f, 0.f, 0.f};
        rsv[tf] = (f32x4){0.f, 0.f, 0.f, 0.f};
    }

    for (int base = 0; base < nv; base += CAP) {
        int rem = nv - base;
        int clen = rem < CAP ? rem : CAP;
        int clenp = (clen + 15) & ~15;
        if (base) __syncthreads();   // prior chunk fully consumed
        for (int idx = tid; idx < clenp * 4; idx += 512) {
            int i = idx >> 2, ch = idx & 3;
            bf16x8 kval = (bf16x8){0, 0, 0, 0, 0, 0, 0, 0};
            bf16x8 vval = (bf16x8){0, 0, 0, 0, 0, 0, 0, 0};
            if (i < clen) {
                size_t ro = (size_t)(base + i) * 512;
                kval = *(const bf16x8*)&kvr[ro + ch * 8];
                vval = *(const bf16x8*)&kvr[ro + 256 + ch * 8];
            }
            *(bf16x8*)&K_lds[i * 40 + ch * 8] = kval;
#pragma unroll
            for (int k = 0; k < 8; ++k)
                Vt_lds[(ch * 8 + k) * VS + i] = vval[k];
        }
        __syncthreads();
        int nfull = clen & ~15;
        for (int l0 = 0; l0 < nfull; l0 += 16)
            attn_step<false>(K_lds, Vt_lds, qf, ctxa, rsv, l0, clen, g, c);
        if (nfull < clenp)
            attn_step<true>(K_lds, Vt_lds, qf, ctxa, rsv, nfull, clen, g, c);
    }
#ifndef HAVE_MFMA16
    asm volatile("s_nop 7\ns_nop 7");
#endif
#pragma unroll
    for (int tf = 0; tf < 2; ++tf) {
        float r = (rsv[tf][0] + rsv[tf][1]) + (rsv[tf][2] + rsv[tf][3]);
        r += __shfl_xor(r, 16);
        r += __shfl_xor(r, 32);
        float inv = 1.f / r;   // rowsum for t-row = c, replicated over groups
#pragma unroll
        for (int rr = 0; rr < 4; ++rr) {
            float invr = __shfl(inv, (lane & 48) | (g * 4 + rr));
            ctxa[tf][0][rr] *= invr;
            ctxa[tf][1][rr] *= invr;
        }
    }
    __syncthreads();   // all waves done with K_lds/Vt_lds; reuse K_lds as staging
    // single-pass ctx write-back: 256 local rows via K_lds[0..256)
    int tl = wid * 32;
#pragma unroll
    for (int tf = 0; tf < 2; ++tf)
#pragma unroll
        for (int df = 0; df < 2; ++df)
#pragma unroll
            for (int rr = 0; rr < 4; ++rr)
                K_lds[(tl + tf * 16 + g * 4 + rr) * 40 + df * 16 + c] =
                    f2bf(ctxa[tf][df][rr]);
    __syncthreads();
    short* cg = ctx + (size_t)bn * 512 * 256 + h * 32 +
                (size_t)half * 256 * 256;
#pragma unroll
    for (int it = 0; it < 2; ++it) {
        int idx = tid + it * 512;
        int l = idx >> 2, ch = idx & 3;
        *(bf16x8*)&cg[(size_t)l * 256 + ch * 8] =
            *(const bf16x8*)&K_lds[l * 40 + ch * 8];
    }
}

// ---------------- fused Wo-GEMM + edge + mean_n ----------------
__global__ __launch_bounds__(256, 3) void wo_final(
    const short* __restrict__ ctx, const short* __restrict__ wo,
    const float* __restrict__ bo, const short* __restrict__ xpe,
    const float* __restrict__ nbr_edge, const float* __restrict__ Wedge,
    const float* __restrict__ bedge, float* __restrict__ out) {
    __shared__ __align__(16) short Ws[64 * 264];
    __shared__ __align__(16) short As[32 * 264];
    __shared__ __align__(16) float edge_s[8][36];
    int bx = blockIdx.x;
    int b = bx >> 6, tt = (bx >> 2) & 15, dt = bx & 3;
    int t0 = tt * 32, d0 = dt * 64;
    int tid = threadIdx.x;
    int wid = tid >> 6, lane = tid & 63;
    int th = wid & 1, dh = wid >> 1;
    int g = lane >> 4, c = lane & 15;

#pragma unroll
    for (int it = 0; it < 8; ++it) {
        int idx = tid + it * 256;
        int r = idx >> 5, kk = (idx & 31) * 8;
        *(bf16x8*)&Ws[r * 264 + kk] =
            *(const bf16x8*)&wo[(size_t)(d0 + r) * 256 + kk];
    }
    int trloc = th * 16 + g * 4;
    int dcol[2];
    float we[2][8], be[2], xb[2][4];
#pragma unroll
    for (int j = 0; j < 2; ++j) {
        dcol[j] = d0 + dh * 32 + j * 16 + c;
#pragma unroll
        for (int cc = 0; cc < 8; ++cc) we[j][cc] = Wedge[dcol[j] * 8 + cc];
        be[j] = bedge[dcol[j]];
        float boj = bo[dcol[j]];
#pragma unroll
        for (int r = 0; r < 4; ++r)
            xb[j][r] = bf2f(xpe[((size_t)b * 512 + t0 + trloc + r) * 256 +
                                dcol[j]]) + boj;
    }
    f32x4 oacc[2] = {(f32x4){0.f, 0.f, 0.f, 0.f}, (f32x4){0.f, 0.f, 0.f, 0.f}};

    for (int n = 0; n < 8; ++n) {
        int bn = b * 8 + n;
#pragma unroll
        for (int it = 0; it < 4; ++it) {
            int idx = tid + it * 256;
            int r = idx >> 5, kk = (idx & 31) * 8;
            *(bf16x8*)&As[r * 264 + kk] =
                *(const bf16x8*)&ctx[((size_t)bn * 512 + t0 + r) * 256 + kk];
        }
        {
            int cc = tid >> 5, tl = tid & 31;
            edge_s[cc][tl] = nbr_edge[((size_t)bn * 8 + cc) * 512 + t0 + tl];
        }
        __syncthreads();
        f32x4 acc[2] = {(f32x4){0.f, 0.f, 0.f, 0.f},
                        (f32x4){0.f, 0.f, 0.f, 0.f}};
#pragma unroll
        for (int k0 = 0; k0 < 8; ++k0) {
            bf16x8 af = *(const bf16x8*)&As[(th * 16 + c) * 264 + k0 * 32 + g * 8];
#pragma unroll
            for (int j = 0; j < 2; ++j) {
                bf16x8 bf = *(const bf16x8*)&Ws[(dh * 32 + j * 16 + c) * 264 +
                                                k0 * 32 + g * 8];
                acc[j] = __builtin_amdgcn_mfma_f32_16x16x32_bf16(af, bf, acc[j],
                                                                 0, 0, 0);
            }
        }
#pragma unroll
        for (int j = 0; j < 2; ++j)
#pragma unroll
            for (int r = 0; r < 4; ++r) {
                float e = be[j];
#pragma unroll
                for (int cc = 0; cc < 8; ++cc)
                    e = fmaf(edge_s[cc][trloc + r], we[j][cc], e);
                oacc[j][r] = fmaf(acc[j][r] + xb[j][r], e, oacc[j][r]);
            }
        __syncthreads();
    }
#pragma unroll
    for (int j = 0; j < 2; ++j)
#pragma unroll
        for (int r = 0; r < 4; ++r)
            out[((size_t)b * 512 + t0 + trloc + r) * 256 + dcol[j]] =
                oacc[j][r] * 0.125f;
}

extern "C" void kernel_launch(void* const* d_in, const int* in_sizes, int n_in,
                              void* d_out, int out_size, void* d_ws, size_t ws_size,
                              hipStream_t stream) {
    const float* x        = (const float*)d_in[0];
    const float* nbr_ts   = (const float*)d_in[1];
    const float* nbr_aux  = (const float*)d_in[2];
    const float* nbr_edge = (const float*)d_in[3];
    const int*   mask     = (const int*)d_in[4];
    const float* Wts  = (const float*)d_in[5];
    const float* bts  = (const float*)d_in[6];
    const float* Waux = (const float*)d_in[7];
    const float* baux = (const float*)d_in[8];
    const float* Wedge= (const float*)d_in[9];
    const float* bedge= (const float*)d_in[10];
    const float* ln_a = (const float*)d_in[11];
    const float* ln_b = (const float*)d_in[12];
    const float* Wq = (const float*)d_in[13];
    const float* bq = (const float*)d_in[14];
    const float* Wk = (const float*)d_in[15];
    const float* bk = (const float*)d_in[16];
    const float* Wv = (const float*)d_in[17];
    const float* bv = (const float*)d_in[18];
    const float* Wo = (const float*)d_in[19];
    const float* bo = (const float*)d_in[20];
    float* out = (float*)d_out;

    char* W = (char*)d_ws;
    float* pe_f    = (float*)(W);                 // 512 KB
    short* xpe_bf  = (short*)(W + 524288);        // 2 MB
    short* qin_bf  = (short*)(W + 4718592);       // 2 MB
    short* q_bf    = (short*)(W + 6815744);       // 2 MB
    short* kvc_bf  = (short*)(W + 8912896);       // 16 MB (compacted kv embed)
    short* kv2c_bf = (short*)(W + 25690112);      // 32 MB (compacted K|V, LDC 512)
    short* ctx_bf  = (short*)(W + 59244544);      // 16 MB
    short* w_bf    = (short*)(W + 92798976);      // 512 KB
    short* W2_bf   = (short*)(W + 93323264);      // 48 KB
    float* bias2_f = (float*)(W + 93372416);      // 1 KB
    float* bkv_f   = (float*)(W + 93373440);      // 2 KB
    int*   pos     = (int*)  (W + 93375488);      // 128 KB
    int*   cnt     = (int*)  (W + 93506560);      // 256 B
    short* wq_bf = w_bf;
    short* wkv_bf = w_bf + 65536;  // wk,wv contiguous => one [512][256] matrix
    short* wo_bf = w_bf + 196608;

    setup_kernel<<<2544, 512, 0, stream>>>(
        Wq, Wk, Wv, Wo, Wts, Waux, bts, baux, bk, bv, x, ln_a, ln_b, mask,
        w_bf, W2_bf, bias2_f, bkv_f, pe_f, pos, cnt, xpe_bf, qin_bf);
    kv_gemm<<<dim3(64, 4), 512, 0, stream>>>(nbr_ts, nbr_aux, W2_bf, bias2_f,
                                             pe_f, pos, kvc_bf);
    proj_gemm<<<1088, 256, 0, stream>>>(qin_bf, kvc_bf, wq_bf, wkv_bf, bq,
                                        bkv_f, cnt, q_bf, kv2c_bf);
    attn_kernel<<<1024, 512, 0, stream>>>(q_bf, kv2c_bf, cnt, ctx_bf);
    wo_final<<<512, 256, 0, stream>>>(ctx_bf, wo_bf, bo, xpe_bf, nbr_edge,
                                      Wedge, bedge, out);
}

// Round 15
// 96.098 us; speedup vs baseline: 1.1417x; 1.0693x over previous
//
#include <hip/hip_runtime.h>
#include <hip/hip_bf16.h>
#include <math.h>

// Dims: B=8, N=8, T=512, L=512, d=256, H=8, dk=32
typedef __attribute__((ext_vector_type(8))) short bf16x8;
typedef __attribute__((ext_vector_type(4))) short bf16x4;
typedef __attribute__((ext_vector_type(4))) float f32x4;

__device__ __forceinline__ short f2bf(float f) {
    return (short)__builtin_bit_cast(unsigned short, __float2bfloat16(f));
}
__device__ __forceinline__ float bf2f(short s) {
    return __builtin_bit_cast(float, ((unsigned)(unsigned short)s) << 16);
}
__device__ __forceinline__ unsigned pk2bf(float a, float b) {
    return ((unsigned)(unsigned short)f2bf(b) << 16) |
           (unsigned)(unsigned short)f2bf(a);
}

#if defined(__has_builtin)
#if __has_builtin(__builtin_amdgcn_mfma_f32_16x16x16bf16_1k)
#define HAVE_MFMA16 1
#endif
#endif

__device__ __forceinline__ f32x4 mfma16(bf16x4 a, bf16x4 b, f32x4 c) {
#ifdef HAVE_MFMA16
    return __builtin_amdgcn_mfma_f32_16x16x16bf16_1k(a, b, c, 0, 0, 0);
#else
    f32x4 d;
    asm volatile("v_mfma_f32_16x16x16_bf16 %0, %1, %2, %3"
                 : "=v"(d) : "v"(a), "v"(b), "v"(c));
    return d;
#endif
}

#define SCALE2 0.25503482403f   // (1/sqrt(32)) * log2(e)
#define CAP 272                  // K/V LDS chunk rows -> 39.9 KB = 4 blocks/CU
#define VS  (CAP + 12)           // Vt row stride 284 shorts: c*VS*2 % 8 == 0 (b64-aligned)

// ---------------- setup: weights->bf16 | W2/bias2/bkv | PE | pos scan | LN ----------------
__global__ __launch_bounds__(512) void setup_kernel(
    const float* __restrict__ Wq, const float* __restrict__ Wk,
    const float* __restrict__ Wv, const float* __restrict__ Wo,
    const float* __restrict__ Wts, const float* __restrict__ Waux,
    const float* __restrict__ bts, const float* __restrict__ baux,
    const float* __restrict__ bk, const float* __restrict__ bv,
    const float* __restrict__ x, const float* __restrict__ ln_a,
    const float* __restrict__ ln_b, const int* __restrict__ mask,
    short* __restrict__ wout, short* __restrict__ W2,
    float* __restrict__ bias2, float* __restrict__ bkv,
    float* __restrict__ pe, int* __restrict__ pos, int* __restrict__ cnt,
    short* __restrict__ xpe_bf, short* __restrict__ qin) {
    __shared__ float redA[8];
    __shared__ float redB[8];
    __shared__ int wsum[8];
    int bid = blockIdx.x, tid = threadIdx.x;
    if (bid < 128) {
        int i = bid * 512 + tid;
        wout[i]          = f2bf(Wq[i]);
        wout[65536 + i]  = f2bf(Wk[i]);
        wout[131072 + i] = f2bf(Wv[i]);
        wout[196608 + i] = f2bf(Wo[i]);
    } else if (bid < 176) {
        int idx = (bid - 128) * 512 + tid;   // 24576
        int e = idx / 96, ch = idx - e * 96;
        float v = 0.f;
        if (ch < 64) { if (e < 192) v = Wts[e * 64 + ch]; }
        else if (ch < 80) { if (e >= 192) v = Waux[(e - 192) * 16 + (ch - 64)]; }
        W2[idx] = f2bf(v);
        if (idx < 256) bias2[idx] = idx < 192 ? bts[idx] : baux[idx - 192];
        if (idx < 512) bkv[idx] = idx < 256 ? bk[idx] : bv[idx - 256];
    } else if (bid < 432) {
        int t = (bid - 176) * 2 + (tid >> 8);
        int dd = tid & 255;
        int i = dd >> 1;
        float div = expf((float)(2 * i) * (-9.210340371976184f / 256.0f));
        float ang = (float)t * div;
        pe[t * 256 + dd] = (dd & 1) ? cosf(ang) : sinf(ang);
    } else if (bid < 496) {
        int bn = bid - 432;
        int lane = tid & 63, wid = tid >> 6;
        int m = mask[bn * 512 + tid] != 0;
        int v = m;
#pragma unroll
        for (int off = 1; off < 64; off <<= 1) {
            int t = __shfl_up(v, off);
            if (lane >= off) v += t;
        }
        if (lane == 63) wsum[wid] = v;
        __syncthreads();
        int base = 0;
#pragma unroll
        for (int w = 0; w < 8; ++w) base += (w < wid) ? wsum[w] : 0;
        pos[bn * 512 + tid] = m ? (base + v - 1) : -1;
        if (tid == 511) cnt[bn] = base + v;
    } else {
        int half = tid >> 8;
        int d = tid & 255;
        int row = (bid - 496) * 2 + half;
        int t = row & 511;
        int i = d >> 1;
        float div = expf((float)(2 * i) * (-9.210340371976184f / 256.0f));
        float ang = (float)t * div;
        float pev = (d & 1) ? cosf(ang) : sinf(ang);
        float v = x[(size_t)row * 256 + d] + pev;
        xpe_bf[(size_t)row * 256 + d] = f2bf(v);
        float s = v;
#pragma unroll
        for (int off = 32; off > 0; off >>= 1) s += __shfl_xor(s, off);
        if ((tid & 63) == 0) redA[tid >> 6] = s;
        __syncthreads();
        int rb = half * 4;
        float mu = (redA[rb] + redA[rb + 1] + redA[rb + 2] + redA[rb + 3]) *
                   (1.0f / 256.0f);
        float dv = v - mu;
        float s2 = dv * dv;
#pragma unroll
        for (int off = 32; off > 0; off >>= 1) s2 += __shfl_xor(s2, off);
        if ((tid & 63) == 0) redB[tid >> 6] = s2;
        __syncthreads();
        float var = (redB[rb] + redB[rb + 1] + redB[rb + 2] + redB[rb + 3]) *
                    (1.0f / 255.0f);
        float sd = sqrtf(var);
        qin[(size_t)row * 256 + d] = f2bf(ln_a[d] * dv / (sd + 1e-6f) + ln_b[d]);
    }
}

// ---------------- kv embed as MFMA GEMM over K=96, scatter to compacted rows ----------------
__global__ __launch_bounds__(512, 2) void kv_gemm(
    const float* __restrict__ nbr_ts, const float* __restrict__ nbr_aux,
    const short* __restrict__ W2, const float* __restrict__ bias2,
    const float* __restrict__ pe, const int* __restrict__ pos,
    short* __restrict__ kvc) {
    __shared__ __align__(16) float S1[64 * 132];
    __shared__ __align__(16) float S2[16 * 132];
    __shared__ __align__(16) short A_lds[128 * 104];
    int tid = threadIdx.x;
    int bn = blockIdx.x, l0 = blockIdx.y * 128;
    const float* tsb = nbr_ts + (size_t)bn * 64 * 512;
    const float* axb = nbr_aux + (size_t)bn * 16 * 512;
#pragma unroll
    for (int it = 0; it < 4; ++it) {
        int idx = tid + it * 512;
        int cc = idx >> 5, lq = idx & 31;
        *(float4*)&S1[cc * 132 + lq * 4] =
            *(const float4*)&tsb[(size_t)cc * 512 + l0 + lq * 4];
    }
    {
        int cc = tid >> 5, lq = tid & 31;
        *(float4*)&S2[cc * 132 + lq * 4] =
            *(const float4*)&axb[(size_t)cc * 512 + l0 + lq * 4];
    }
    __syncthreads();
#pragma unroll
    for (int p = 0; p < 3; ++p) {
        int tk = tid + p * 512;
        int l = tk & 127, chunk = tk >> 7;
        union { bf16x8 v; unsigned u[4]; } v8;
        if (chunk < 8) {
#pragma unroll
            for (int i = 0; i < 4; ++i)
                v8.u[i] = pk2bf(S1[(chunk * 8 + 2 * i) * 132 + l],
                                S1[(chunk * 8 + 2 * i + 1) * 132 + l]);
        } else if (chunk < 10) {
#pragma unroll
            for (int i = 0; i < 4; ++i)
                v8.u[i] = pk2bf(S2[((chunk - 8) * 8 + 2 * i) * 132 + l],
                                S2[((chunk - 8) * 8 + 2 * i + 1) * 132 + l]);
        } else {
#pragma unroll
            for (int i = 0; i < 4; ++i) v8.u[i] = 0;
        }
        *(bf16x8*)&A_lds[l * 104 + chunk * 8] = v8.v;
    }
    __syncthreads();
    int wid = tid >> 6, lane = tid & 63;
    int g = lane >> 4, c = lane & 15;
    int lm = wid >> 2, le = wid & 3;
    bf16x8 wf[4][3];
#pragma unroll
    for (int nf = 0; nf < 4; ++nf)
#pragma unroll
        for (int ks = 0; ks < 3; ++ks)
            wf[nf][ks] = *(const bf16x8*)&W2[(size_t)(le * 64 + nf * 16 + c) * 96 +
                                             ks * 32 + g * 8];
    f32x4 acc[4][4];
#pragma unroll
    for (int i = 0; i < 4; ++i)
#pragma unroll
        for (int j = 0; j < 4; ++j) acc[i][j] = (f32x4){0.f, 0.f, 0.f, 0.f};
#pragma unroll
    for (int ks = 0; ks < 3; ++ks) {
#pragma unroll
        for (int mf = 0; mf < 4; ++mf) {
            bf16x8 af = *(const bf16x8*)&A_lds[(lm * 64 + mf * 16 + c) * 104 +
                                               ks * 32 + g * 8];
#pragma unroll
            for (int nf = 0; nf < 4; ++nf)
                acc[mf][nf] = __builtin_amdgcn_mfma_f32_16x16x32_bf16(
                    af, wf[nf][ks], acc[mf][nf], 0, 0, 0);
        }
    }
    float b2c[4];
#pragma unroll
    for (int nf = 0; nf < 4; ++nf) b2c[nf] = bias2[le * 64 + nf * 16 + c];
    short* kvb = kvc + (size_t)bn * 512 * 256;
    const int* posb = pos + bn * 512 + l0;
#pragma unroll
    for (int mf = 0; mf < 4; ++mf) {
#pragma unroll
        for (int r = 0; r < 4; ++r) {
            int lr = lm * 64 + mf * 16 + g * 4 + r;
            int p = posb[lr];
            if (p >= 0) {
#pragma unroll
                for (int nf = 0; nf < 4; ++nf) {
                    int e = le * 64 + nf * 16 + c;
                    kvb[(size_t)p * 256 + e] =
                        f2bf(acc[mf][nf][r] + b2c[nf] +
                             pe[(size_t)(l0 + lr) * 256 + e]);
                }
            }
        }
    }
}

// ---------------- merged q-projection + compact K|V projection ----------------
__global__ __launch_bounds__(256) void proj_gemm(
    const short* __restrict__ qin, const short* __restrict__ kvc,
    const short* __restrict__ wq, const short* __restrict__ wkv,
    const float* __restrict__ bq, const float* __restrict__ bkv,
    const int* __restrict__ cnt, short* __restrict__ qout,
    short* __restrict__ kv2) {
    int bx = blockIdx.x;
    const short* A; const short* Wm; const float* bias; short* C;
    int row0, col0, LDC; float esc;
    if (bx < 64) {
        row0 = (bx >> 1) * 128; col0 = (bx & 1) * 128;
        A = qin; Wm = wq; bias = bq; C = qout; LDC = 256; esc = SCALE2;
    } else {
        int idx = bx - 64;               // 1024 = bn(64) x mt(4) x ct(4)
        int bn = idx >> 4, mt = (idx >> 2) & 3, ct = idx & 3;
        int nvp = (cnt[bn] + 15) & ~15;
        row0 = mt * 128;
        if (row0 >= nvp) return;
        col0 = ct * 128;
        A = kvc + (size_t)bn * 512 * 256; Wm = wkv; bias = bkv;
        C = kv2 + (size_t)bn * 512 * 512; LDC = 512; esc = 1.0f;
    }
    __shared__ __align__(16) short As[128 * 40];
    __shared__ __align__(16) short Bs[128 * 40];
    int tid = threadIdx.x;
    int wid = tid >> 6, lane = tid & 63;
    int wm = wid >> 1, wn = wid & 1;
    int g = lane >> 4, c = lane & 15;
    f32x4 acc[4][4];
#pragma unroll
    for (int i = 0; i < 4; ++i)
#pragma unroll
        for (int j = 0; j < 4; ++j) acc[i][j] = (f32x4){0.f, 0.f, 0.f, 0.f};

    for (int k0 = 0; k0 < 256; k0 += 32) {
#pragma unroll
        for (int it = 0; it < 2; ++it) {
            int idx = tid + it * 256;
            int r = idx >> 2, ch = idx & 3;
            *(bf16x8*)&As[r * 40 + ch * 8] =
                *(const bf16x8*)&A[(size_t)(row0 + r) * 256 + k0 + ch * 8];
            *(bf16x8*)&Bs[r * 40 + ch * 8] =
                *(const bf16x8*)&Wm[(size_t)(col0 + r) * 256 + k0 + ch * 8];
        }
        __syncthreads();
        bf16x8 af[4], bfr[4];
#pragma unroll
        for (int mf = 0; mf < 4; ++mf)
            af[mf] = *(const bf16x8*)&As[(wm * 64 + mf * 16 + c) * 40 + g * 8];
#pragma unroll
        for (int nf = 0; nf < 4; ++nf)
            bfr[nf] = *(const bf16x8*)&Bs[(wn * 64 + nf * 16 + c) * 40 + g * 8];
#pragma unroll
        for (int mf = 0; mf < 4; ++mf)
#pragma unroll
            for (int nf = 0; nf < 4; ++nf)
                acc[mf][nf] = __builtin_amdgcn_mfma_f32_16x16x32_bf16(
                    af[mf], bfr[nf], acc[mf][nf], 0, 0, 0);
        __syncthreads();
    }
#pragma unroll
    for (int nf = 0; nf < 4; ++nf) {
        int col = col0 + wn * 64 + nf * 16 + c;
        float bz = bias[col];
#pragma unroll
        for (int mf = 0; mf < 4; ++mf)
#pragma unroll
            for (int r = 0; r < 4; ++r) {
                int row = row0 + wm * 64 + mf * 16 + g * 4 + r;
                C[(size_t)row * LDC + col] = f2bf((acc[mf][nf][r] + bz) * esc);
            }
    }
}

// ---------------- fused MFMA attention, compacted K/V, t-split 2-way ----------------
// grid 1024 = (bn, h, t-half). 8 waves; wave owns 32 t rows (2 t-frags).
// CAP=272 -> LDS 39.9KB -> 4 blocks/CU resident = exactly one full round.
template <bool MASKED>
__device__ __forceinline__ void attn_step(
    const short* K_lds, const short* Vt_lds, const bf16x8* qf,
    f32x4 (*ctxa)[2], f32x4* rsv, int l0, int clen, int g, int c) {
    bf16x8 ak = *(const bf16x8*)&K_lds[(l0 + c) * 40 + g * 8];
    bf16x4 vb0 = *(const bf16x4*)&Vt_lds[c * VS + l0 + g * 4];
    bf16x4 vb1 = *(const bf16x4*)&Vt_lds[(16 + c) * VS + l0 + g * 4];
    int lb = l0 + g * 4;
#pragma unroll
    for (int tf = 0; tf < 2; ++tf) {
        f32x4 s = __builtin_amdgcn_mfma_f32_16x16x32_bf16(
            ak, qf[tf], (f32x4){0.f, 0.f, 0.f, 0.f}, 0, 0, 0);
        float p0 = exp2f(s[0]);
        float p1 = exp2f(s[1]);
        float p2 = exp2f(s[2]);
        float p3 = exp2f(s[3]);
        if (MASKED) {
            p0 = (lb + 0 < clen) ? p0 : 0.f;
            p1 = (lb + 1 < clen) ? p1 : 0.f;
            p2 = (lb + 2 < clen) ? p2 : 0.f;
            p3 = (lb + 3 < clen) ? p3 : 0.f;
        }
        rsv[tf] += (f32x4){p0, p1, p2, p3};
        union { bf16x4 v; unsigned u[2]; } pu;
        pu.u[0] = pk2bf(p0, p1);
        pu.u[1] = pk2bf(p2, p3);
        __builtin_amdgcn_s_setprio(1);
        ctxa[tf][0] = mfma16(pu.v, vb0, ctxa[tf][0]);
        ctxa[tf][1] = mfma16(pu.v, vb1, ctxa[tf][1]);
        __builtin_amdgcn_s_setprio(0);
    }
}

__global__ __launch_bounds__(512, 8) void attn_kernel(
    const short* __restrict__ Q, const short* __restrict__ KV2,
    const int* __restrict__ cnt, short* __restrict__ ctx) {
    __shared__ __align__(16) short K_lds[CAP * 40];
    __shared__ __align__(16) short Vt_lds[32 * VS];
    int tid = threadIdx.x;
    int bx = blockIdx.x;
    int half = bx & 1, h = (bx >> 1) & 7, bn = bx >> 4, b = bn >> 3;
    int nv = cnt[bn];
    const short* kvr = KV2 + (size_t)bn * 512 * 512 + h * 32;

    int wid = tid >> 6, lane = tid & 63;
    int g = lane >> 4, c = lane & 15;
    int t0 = half * 256 + wid * 32;
    const short* qg = Q + ((size_t)b * 512 + t0 + c) * 256 + h * 32 + g * 8;
    bf16x8 qf[2];
#pragma unroll
    for (int tf = 0; tf < 2; ++tf)
        qf[tf] = *(const bf16x8*)&qg[(size_t)tf * 16 * 256];

    f32x4 ctxa[2][2];
    f32x4 rsv[2];
#pragma unroll
    for (int tf = 0; tf < 2; ++tf) {
        ctxa[tf][0] = (f32x4){0.f, 0.f, 0.f, 0.f};
        ctxa[tf][1] = (f32x4){0.f, 0.f, 0.f, 0.f};
        rsv[tf] = (f32x4){0.f, 0.f, 0.f, 0.f};
    }

    for (int base = 0; base < nv; base += CAP) {
        int rem = nv - base;
        int clen = rem < CAP ? rem : CAP;
        int clenp = (clen + 15) & ~15;
        if (base) __syncthreads();   // prior chunk fully consumed
        for (int idx = tid; idx < clenp * 4; idx += 512) {
            int i = idx >> 2, ch = idx & 3;
            bf16x8 kval = (bf16x8){0, 0, 0, 0, 0, 0, 0, 0};
            bf16x8 vval = (bf16x8){0, 0, 0, 0, 0, 0, 0, 0};
            if (i < clen) {
                size_t ro = (size_t)(base + i) * 512;
                kval = *(const bf16x8*)&kvr[ro + ch * 8];
                vval = *(const bf16x8*)&kvr[ro + 256 + ch * 8];
            }
            *(bf16x8*)&K_lds[i * 40 + ch * 8] = kval;
#pragma unroll
            for (int k = 0; k < 8; ++k)
                Vt_lds[(ch * 8 + k) * VS + i] = vval[k];
        }
        __syncthreads();
        int nfull = clen & ~15;
        for (int l0 = 0; l0 < nfull; l0 += 16)
            attn_step<false>(K_lds, Vt_lds, qf, ctxa, rsv, l0, clen, g, c);
        if (nfull < clenp)
            attn_step<true>(K_lds, Vt_lds, qf, ctxa, rsv, nfull, clen, g, c);
    }
#ifndef HAVE_MFMA16
    asm volatile("s_nop 7\ns_nop 7");
#endif
#pragma unroll
    for (int tf = 0; tf < 2; ++tf) {
        float r = (rsv[tf][0] + rsv[tf][1]) + (rsv[tf][2] + rsv[tf][3]);
        r += __shfl_xor(r, 16);
        r += __shfl_xor(r, 32);
        float inv = 1.f / r;   // rowsum for t-row = c, replicated over groups
#pragma unroll
        for (int rr = 0; rr < 4; ++rr) {
            float invr = __shfl(inv, (lane & 48) | (g * 4 + rr));
            ctxa[tf][0][rr] *= invr;
            ctxa[tf][1][rr] *= invr;
        }
    }
    __syncthreads();   // all waves done with K_lds/Vt_lds; reuse K_lds as staging
    // single-pass ctx write-back: 256 local rows via K_lds[0..256)
    int tl = wid * 32;
#pragma unroll
    for (int tf = 0; tf < 2; ++tf)
#pragma unroll
        for (int df = 0; df < 2; ++df)
#pragma unroll
            for (int rr = 0; rr < 4; ++rr)
                K_lds[(tl + tf * 16 + g * 4 + rr) * 40 + df * 16 + c] =
                    f2bf(ctxa[tf][df][rr]);
    __syncthreads();
    short* cg = ctx + (size_t)bn * 512 * 256 + h * 32 +
                (size_t)half * 256 * 256;
#pragma unroll
    for (int it = 0; it < 2; ++it) {
        int idx = tid + it * 512;
        int l = idx >> 2, ch = idx & 3;
        *(bf16x8*)&cg[(size_t)l * 256 + ch * 8] =
            *(const bf16x8*)&K_lds[l * 40 + ch * 8];
    }
}

// ---------------- fused Wo-GEMM + edge + mean_n (T14 async-STAGE split) ----------------
__global__ __launch_bounds__(256, 3) void wo_final(
    const short* __restrict__ ctx, const short* __restrict__ wo,
    const float* __restrict__ bo, const short* __restrict__ xpe,
    const float* __restrict__ nbr_edge, const float* __restrict__ Wedge,
    const float* __restrict__ bedge, float* __restrict__ out) {
    __shared__ __align__(16) short Ws[64 * 264];
    __shared__ __align__(16) short As[32 * 264];
    __shared__ __align__(16) float edge_s[8][36];
    int bx = blockIdx.x;
    int b = bx >> 6, tt = (bx >> 2) & 15, dt = bx & 3;
    int t0 = tt * 32, d0 = dt * 64;
    int tid = threadIdx.x;
    int wid = tid >> 6, lane = tid & 63;
    int th = wid & 1, dh = wid >> 1;
    int g = lane >> 4, c = lane & 15;

#pragma unroll
    for (int it = 0; it < 8; ++it) {
        int idx = tid + it * 256;
        int r = idx >> 5, kk = (idx & 31) * 8;
        *(bf16x8*)&Ws[r * 264 + kk] =
            *(const bf16x8*)&wo[(size_t)(d0 + r) * 256 + kk];
    }
    int trloc = th * 16 + g * 4;
    int dcol[2];
    float we[2][8], be[2], xb[2][4];
#pragma unroll
    for (int j = 0; j < 2; ++j) {
        dcol[j] = d0 + dh * 32 + j * 16 + c;
#pragma unroll
        for (int cc = 0; cc < 8; ++cc) we[j][cc] = Wedge[dcol[j] * 8 + cc];
        be[j] = bedge[dcol[j]];
        float boj = bo[dcol[j]];
#pragma unroll
        for (int r = 0; r < 4; ++r)
            xb[j][r] = bf2f(xpe[((size_t)b * 512 + t0 + trloc + r) * 256 +
                                dcol[j]]) + boj;
    }
    f32x4 oacc[2] = {(f32x4){0.f, 0.f, 0.f, 0.f}, (f32x4){0.f, 0.f, 0.f, 0.f}};

    int sr = tid >> 5, skk = (tid & 31) * 8;   // staging coords (4 rows/thread)
    int ec = tid >> 5, etl = tid & 31;         // edge coords
    // prologue: load n=0 into regs
    bf16x8 rv[4];
    float ev;
    {
        int bn = b * 8;
#pragma unroll
        for (int it = 0; it < 4; ++it)
            rv[it] = *(const bf16x8*)&ctx[((size_t)bn * 512 + t0 + sr + it * 8) *
                                          256 + skk];
        ev = nbr_edge[((size_t)bn * 8 + ec) * 512 + t0 + etl];
    }

    for (int n = 0; n < 8; ++n) {
        // write staged regs for this n
#pragma unroll
        for (int it = 0; it < 4; ++it)
            *(bf16x8*)&As[(sr + it * 8) * 264 + skk] = rv[it];
        edge_s[ec][etl] = ev;
        __syncthreads();
        // issue next n's loads (latency hides under MFMA below)
        if (n < 7) {
            int bn = b * 8 + n + 1;
#pragma unroll
            for (int it = 0; it < 4; ++it)
                rv[it] = *(const bf16x8*)&ctx[((size_t)bn * 512 + t0 + sr +
                                              it * 8) * 256 + skk];
            ev = nbr_edge[((size_t)bn * 8 + ec) * 512 + t0 + etl];
        }
        f32x4 acc[2] = {(f32x4){0.f, 0.f, 0.f, 0.f},
                        (f32x4){0.f, 0.f, 0.f, 0.f}};
#pragma unroll
        for (int k0 = 0; k0 < 8; ++k0) {
            bf16x8 af = *(const bf16x8*)&As[(th * 16 + c) * 264 + k0 * 32 + g * 8];
#pragma unroll
            for (int j = 0; j < 2; ++j) {
                bf16x8 bf = *(const bf16x8*)&Ws[(dh * 32 + j * 16 + c) * 264 +
                                                k0 * 32 + g * 8];
                acc[j] = __builtin_amdgcn_mfma_f32_16x16x32_bf16(af, bf, acc[j],
                                                                 0, 0, 0);
            }
        }
#pragma unroll
        for (int j = 0; j < 2; ++j)
#pragma unroll
            for (int r = 0; r < 4; ++r) {
                float e = be[j];
#pragma unroll
                for (int cc = 0; cc < 8; ++cc)
                    e = fmaf(edge_s[cc][trloc + r], we[j][cc], e);
                oacc[j][r] = fmaf(acc[j][r] + xb[j][r], e, oacc[j][r]);
            }
        __syncthreads();   // all reads of As/edge_s done before next write
    }
#pragma unroll
    for (int j = 0; j < 2; ++j)
#pragma unroll
        for (int r = 0; r < 4; ++r)
            out[((size_t)b * 512 + t0 + trloc + r) * 256 + dcol[j]] =
                oacc[j][r] * 0.125f;
}

extern "C" void kernel_launch(void* const* d_in, const int* in_sizes, int n_in,
                              void* d_out, int out_size, void* d_ws, size_t ws_size,
                              hipStream_t stream) {
    const float* x        = (const float*)d_in[0];
    const float* nbr_ts   = (const float*)d_in[1];
    const float* nbr_aux  = (const float*)d_in[2];
    const float* nbr_edge = (const float*)d_in[3];
    const int*   mask     = (const int*)d_in[4];
    const float* Wts  = (const float*)d_in[5];
    const float* bts  = (const float*)d_in[6];
    const float* Waux = (const float*)d_in[7];
    const float* baux = (const float*)d_in[8];
    const float* Wedge= (const float*)d_in[9];
    const float* bedge= (const float*)d_in[10];
    const float* ln_a = (const float*)d_in[11];
    const float* ln_b = (const float*)d_in[12];
    const float* Wq = (const float*)d_in[13];
    const float* bq = (const float*)d_in[14];
    const float* Wk = (const float*)d_in[15];
    const float* bk = (const float*)d_in[16];
    const float* Wv = (const float*)d_in[17];
    const float* bv = (const float*)d_in[18];
    const float* Wo = (const float*)d_in[19];
    const float* bo = (const float*)d_in[20];
    float* out = (float*)d_out;

    char* W = (char*)d_ws;
    float* pe_f    = (float*)(W);                 // 512 KB
    short* xpe_bf  = (short*)(W + 524288);        // 2 MB
    short* qin_bf  = (short*)(W + 4718592);       // 2 MB
    short* q_bf    = (short*)(W + 6815744);       // 2 MB
    short* kvc_bf  = (short*)(W + 8912896);       // 16 MB (compacted kv embed)
    short* kv2c_bf = (short*)(W + 25690112);      // 32 MB (compacted K|V, LDC 512)
    short* ctx_bf  = (short*)(W + 59244544);      // 16 MB
    short* w_bf    = (short*)(W + 92798976);      // 512 KB
    short* W2_bf   = (short*)(W + 93323264);      // 48 KB
    float* bias2_f = (float*)(W + 93372416);      // 1 KB
    float* bkv_f   = (float*)(W + 93373440);      // 2 KB
    int*   pos     = (int*)  (W + 93375488);      // 128 KB
    int*   cnt     = (int*)  (W + 93506560);      // 256 B
    short* wq_bf = w_bf;
    short* wkv_bf = w_bf + 65536;  // wk,wv contiguous => one [512][256] matrix
    short* wo_bf = w_bf + 196608;

    setup_kernel<<<2544, 512, 0, stream>>>(
        Wq, Wk, Wv, Wo, Wts, Waux, bts, baux, bk, bv, x, ln_a, ln_b, mask,
        w_bf, W2_bf, bias2_f, bkv_f, pe_f, pos, cnt, xpe_bf, qin_bf);
    kv_gemm<<<dim3(64, 4), 512, 0, stream>>>(nbr_ts, nbr_aux, W2_bf, bias2_f,
                                             pe_f, pos, kvc_bf);
    proj_gemm<<<1088, 256, 0, stream>>>(qin_bf, kvc_bf, wq_bf, wkv_bf, bq,
                                        bkv_f, cnt, q_bf, kv2c_bf);
    attn_kernel<<<1024, 512, 0, stream>>>(q_bf, kv2c_bf, cnt, ctx_bf);
    wo_final<<<512, 256, 0, stream>>>(ctx_bf, wo_bf, bo, xpe_bf, nbr_edge,
                                      Wedge, bedge, out);
}

// Round 16
// 96.094 us; speedup vs baseline: 1.1418x; 1.0000x over previous
//
#include <hip/hip_runtime.h>
#include <hip/hip_bf16.h>
#include <math.h>

// Dims: B=8, N=8, T=512, L=512, d=256, H=8, dk=32
typedef __attribute__((ext_vector_type(8))) short bf16x8;
typedef __attribute__((ext_vector_type(4))) short bf16x4;
typedef __attribute__((ext_vector_type(4))) float f32x4;

__device__ __forceinline__ short f2bf(float f) {
    return (short)__builtin_bit_cast(unsigned short, __float2bfloat16(f));
}
__device__ __forceinline__ float bf2f(short s) {
    return __builtin_bit_cast(float, ((unsigned)(unsigned short)s) << 16);
}
__device__ __forceinline__ unsigned pk2bf(float a, float b) {
    return ((unsigned)(unsigned short)f2bf(b) << 16) |
           (unsigned)(unsigned short)f2bf(a);
}

#if defined(__has_builtin)
#if __has_builtin(__builtin_amdgcn_mfma_f32_16x16x16bf16_1k)
#define HAVE_MFMA16 1
#endif
#endif

__device__ __forceinline__ f32x4 mfma16(bf16x4 a, bf16x4 b, f32x4 c) {
#ifdef HAVE_MFMA16
    return __builtin_amdgcn_mfma_f32_16x16x16bf16_1k(a, b, c, 0, 0, 0);
#else
    f32x4 d;
    asm volatile("v_mfma_f32_16x16x16_bf16 %0, %1, %2, %3"
                 : "=v"(d) : "v"(a), "v"(b), "v"(c));
    return d;
#endif
}

#define SCALE2 0.25503482403f   // (1/sqrt(32)) * log2(e)
#define CAP 272                  // K/V LDS chunk rows -> 39.9 KB = 4 blocks/CU
#define VS  (CAP + 12)           // Vt row stride 284 shorts: c*VS*2 % 8 == 0 (b64-aligned)

// ---------------- setup: weights->bf16 | W2/bias2/bkv | PE | pos scan | LN ----------------
__global__ __launch_bounds__(512) void setup_kernel(
    const float* __restrict__ Wq, const float* __restrict__ Wk,
    const float* __restrict__ Wv, const float* __restrict__ Wo,
    const float* __restrict__ Wts, const float* __restrict__ Waux,
    const float* __restrict__ bts, const float* __restrict__ baux,
    const float* __restrict__ bk, const float* __restrict__ bv,
    const float* __restrict__ x, const float* __restrict__ ln_a,
    const float* __restrict__ ln_b, const int* __restrict__ mask,
    short* __restrict__ wout, short* __restrict__ W2,
    float* __restrict__ bias2, float* __restrict__ bkv,
    float* __restrict__ pe, int* __restrict__ pos, int* __restrict__ cnt,
    short* __restrict__ xpe_bf, short* __restrict__ qin) {
    __shared__ float redA[8];
    __shared__ float redB[8];
    __shared__ int wsum[8];
    int bid = blockIdx.x, tid = threadIdx.x;
    if (bid < 128) {
        int i = bid * 512 + tid;
        wout[i]          = f2bf(Wq[i]);
        wout[65536 + i]  = f2bf(Wk[i]);
        wout[131072 + i] = f2bf(Wv[i]);
        wout[196608 + i] = f2bf(Wo[i]);
    } else if (bid < 176) {
        int idx = (bid - 128) * 512 + tid;   // 24576
        int e = idx / 96, ch = idx - e * 96;
        float v = 0.f;
        if (ch < 64) { if (e < 192) v = Wts[e * 64 + ch]; }
        else if (ch < 80) { if (e >= 192) v = Waux[(e - 192) * 16 + (ch - 64)]; }
        W2[idx] = f2bf(v);
        if (idx < 256) bias2[idx] = idx < 192 ? bts[idx] : baux[idx - 192];
        if (idx < 512) bkv[idx] = idx < 256 ? bk[idx] : bv[idx - 256];
    } else if (bid < 432) {
        int t = (bid - 176) * 2 + (tid >> 8);
        int dd = tid & 255;
        int i = dd >> 1;
        float div = expf((float)(2 * i) * (-9.210340371976184f / 256.0f));
        float ang = (float)t * div;
        pe[t * 256 + dd] = (dd & 1) ? cosf(ang) : sinf(ang);
    } else if (bid < 496) {
        int bn = bid - 432;
        int lane = tid & 63, wid = tid >> 6;
        int m = mask[bn * 512 + tid] != 0;
        int v = m;
#pragma unroll
        for (int off = 1; off < 64; off <<= 1) {
            int t = __shfl_up(v, off);
            if (lane >= off) v += t;
        }
        if (lane == 63) wsum[wid] = v;
        __syncthreads();
        int base = 0;
#pragma unroll
        for (int w = 0; w < 8; ++w) base += (w < wid) ? wsum[w] : 0;
        pos[bn * 512 + tid] = m ? (base + v - 1) : -1;
        if (tid == 511) cnt[bn] = base + v;
    } else {
        int half = tid >> 8;
        int d = tid & 255;
        int row = (bid - 496) * 2 + half;
        int t = row & 511;
        int i = d >> 1;
        float div = expf((float)(2 * i) * (-9.210340371976184f / 256.0f));
        float ang = (float)t * div;
        float pev = (d & 1) ? cosf(ang) : sinf(ang);
        float v = x[(size_t)row * 256 + d] + pev;
        xpe_bf[(size_t)row * 256 + d] = f2bf(v);
        float s = v;
#pragma unroll
        for (int off = 32; off > 0; off >>= 1) s += __shfl_xor(s, off);
        if ((tid & 63) == 0) redA[tid >> 6] = s;
        __syncthreads();
        int rb = half * 4;
        float mu = (redA[rb] + redA[rb + 1] + redA[rb + 2] + redA[rb + 3]) *
                   (1.0f / 256.0f);
        float dv = v - mu;
        float s2 = dv * dv;
#pragma unroll
        for (int off = 32; off > 0; off >>= 1) s2 += __shfl_xor(s2, off);
        if ((tid & 63) == 0) redB[tid >> 6] = s2;
        __syncthreads();
        float var = (redB[rb] + redB[rb + 1] + redB[rb + 2] + redB[rb + 3]) *
                    (1.0f / 255.0f);
        float sd = sqrtf(var);
        qin[(size_t)row * 256 + d] = f2bf(ln_a[d] * dv / (sd + 1e-6f) + ln_b[d]);
    }
}

// ---------------- kv embed as MFMA GEMM over K=96, scatter to compacted rows ----------------
__global__ __launch_bounds__(512, 2) void kv_gemm(
    const float* __restrict__ nbr_ts, const float* __restrict__ nbr_aux,
    const short* __restrict__ W2, const float* __restrict__ bias2,
    const float* __restrict__ pe, const int* __restrict__ pos,
    short* __restrict__ kvc) {
    __shared__ __align__(16) float S1[64 * 132];
    __shared__ __align__(16) float S2[16 * 132];
    __shared__ __align__(16) short A_lds[128 * 104];
    int tid = threadIdx.x;
    int bn = blockIdx.x, l0 = blockIdx.y * 128;
    const float* tsb = nbr_ts + (size_t)bn * 64 * 512;
    const float* axb = nbr_aux + (size_t)bn * 16 * 512;
#pragma unroll
    for (int it = 0; it < 4; ++it) {
        int idx = tid + it * 512;
        int cc = idx >> 5, lq = idx & 31;
        *(float4*)&S1[cc * 132 + lq * 4] =
            *(const float4*)&tsb[(size_t)cc * 512 + l0 + lq * 4];
    }
    {
        int cc = tid >> 5, lq = tid & 31;
        *(float4*)&S2[cc * 132 + lq * 4] =
            *(const float4*)&axb[(size_t)cc * 512 + l0 + lq * 4];
    }
    __syncthreads();
#pragma unroll
    for (int p = 0; p < 3; ++p) {
        int tk = tid + p * 512;
        int l = tk & 127, chunk = tk >> 7;
        union { bf16x8 v; unsigned u[4]; } v8;
        if (chunk < 8) {
#pragma unroll
            for (int i = 0; i < 4; ++i)
                v8.u[i] = pk2bf(S1[(chunk * 8 + 2 * i) * 132 + l],
                                S1[(chunk * 8 + 2 * i + 1) * 132 + l]);
        } else if (chunk < 10) {
#pragma unroll
            for (int i = 0; i < 4; ++i)
                v8.u[i] = pk2bf(S2[((chunk - 8) * 8 + 2 * i) * 132 + l],
                                S2[((chunk - 8) * 8 + 2 * i + 1) * 132 + l]);
        } else {
#pragma unroll
            for (int i = 0; i < 4; ++i) v8.u[i] = 0;
        }
        *(bf16x8*)&A_lds[l * 104 + chunk * 8] = v8.v;
    }
    __syncthreads();
    int wid = tid >> 6, lane = tid & 63;
    int g = lane >> 4, c = lane & 15;
    int lm = wid >> 2, le = wid & 3;
    bf16x8 wf[4][3];
#pragma unroll
    for (int nf = 0; nf < 4; ++nf)
#pragma unroll
        for (int ks = 0; ks < 3; ++ks)
            wf[nf][ks] = *(const bf16x8*)&W2[(size_t)(le * 64 + nf * 16 + c) * 96 +
                                             ks * 32 + g * 8];
    f32x4 acc[4][4];
#pragma unroll
    for (int i = 0; i < 4; ++i)
#pragma unroll
        for (int j = 0; j < 4; ++j) acc[i][j] = (f32x4){0.f, 0.f, 0.f, 0.f};
#pragma unroll
    for (int ks = 0; ks < 3; ++ks) {
#pragma unroll
        for (int mf = 0; mf < 4; ++mf) {
            bf16x8 af = *(const bf16x8*)&A_lds[(lm * 64 + mf * 16 + c) * 104 +
                                               ks * 32 + g * 8];
#pragma unroll
            for (int nf = 0; nf < 4; ++nf)
                acc[mf][nf] = __builtin_amdgcn_mfma_f32_16x16x32_bf16(
                    af, wf[nf][ks], acc[mf][nf], 0, 0, 0);
        }
    }
    float b2c[4];
#pragma unroll
    for (int nf = 0; nf < 4; ++nf) b2c[nf] = bias2[le * 64 + nf * 16 + c];
    short* kvb = kvc + (size_t)bn * 512 * 256;
    const int* posb = pos + bn * 512 + l0;
#pragma unroll
    for (int mf = 0; mf < 4; ++mf) {
#pragma unroll
        for (int r = 0; r < 4; ++r) {
            int lr = lm * 64 + mf * 16 + g * 4 + r;
            int p = posb[lr];
            if (p >= 0) {
#pragma unroll
                for (int nf = 0; nf < 4; ++nf) {
                    int e = le * 64 + nf * 16 + c;
                    kvb[(size_t)p * 256 + e] =
                        f2bf(acc[mf][nf][r] + b2c[nf] +
                             pe[(size_t)(l0 + lr) * 256 + e]);
                }
            }
        }
    }
}

// ---------------- merged q-projection + compact K|V projection ----------------
// T14 reg-prefetch: k0+1 global loads issued before k0's MFMA block.
__global__ __launch_bounds__(256) void proj_gemm(
    const short* __restrict__ qin, const short* __restrict__ kvc,
    const short* __restrict__ wq, const short* __restrict__ wkv,
    const float* __restrict__ bq, const float* __restrict__ bkv,
    const int* __restrict__ cnt, short* __restrict__ qout,
    short* __restrict__ kv2) {
    int bx = blockIdx.x;
    const short* A; const short* Wm; const float* bias; short* C;
    int row0, col0, LDC; float esc;
    if (bx < 64) {
        row0 = (bx >> 1) * 128; col0 = (bx & 1) * 128;
        A = qin; Wm = wq; bias = bq; C = qout; LDC = 256; esc = SCALE2;
    } else {
        int idx = bx - 64;               // 1024 = bn(64) x mt(4) x ct(4)
        int bn = idx >> 4, mt = (idx >> 2) & 3, ct = idx & 3;
        int nvp = (cnt[bn] + 15) & ~15;
        row0 = mt * 128;
        if (row0 >= nvp) return;
        col0 = ct * 128;
        A = kvc + (size_t)bn * 512 * 256; Wm = wkv; bias = bkv;
        C = kv2 + (size_t)bn * 512 * 512; LDC = 512; esc = 1.0f;
    }
    __shared__ __align__(16) short As[128 * 40];
    __shared__ __align__(16) short Bs[128 * 40];
    int tid = threadIdx.x;
    int wid = tid >> 6, lane = tid & 63;
    int wm = wid >> 1, wn = wid & 1;
    int g = lane >> 4, c = lane & 15;
    f32x4 acc[4][4];
#pragma unroll
    for (int i = 0; i < 4; ++i)
#pragma unroll
        for (int j = 0; j < 4; ++j) acc[i][j] = (f32x4){0.f, 0.f, 0.f, 0.f};

    // staging coords (2 chunks per thread)
    int r0s = tid >> 2, ch0 = (tid & 3) * 8;
    int r1s = (tid + 256) >> 2, ch1 = ((tid + 256) & 3) * 8;
    // prologue: k0 = 0 into regs
    bf16x8 a0 = *(const bf16x8*)&A[(size_t)(row0 + r0s) * 256 + ch0];
    bf16x8 b0 = *(const bf16x8*)&Wm[(size_t)(col0 + r0s) * 256 + ch0];
    bf16x8 a1 = *(const bf16x8*)&A[(size_t)(row0 + r1s) * 256 + ch1];
    bf16x8 b1 = *(const bf16x8*)&Wm[(size_t)(col0 + r1s) * 256 + ch1];

    for (int k0 = 0; k0 < 256; k0 += 32) {
        *(bf16x8*)&As[r0s * 40 + ch0] = a0;
        *(bf16x8*)&Bs[r0s * 40 + ch0] = b0;
        *(bf16x8*)&As[r1s * 40 + ch1] = a1;
        *(bf16x8*)&Bs[r1s * 40 + ch1] = b1;
        __syncthreads();
        if (k0 < 224) {
            int kn = k0 + 32;
            a0 = *(const bf16x8*)&A[(size_t)(row0 + r0s) * 256 + kn + ch0];
            b0 = *(const bf16x8*)&Wm[(size_t)(col0 + r0s) * 256 + kn + ch0];
            a1 = *(const bf16x8*)&A[(size_t)(row0 + r1s) * 256 + kn + ch1];
            b1 = *(const bf16x8*)&Wm[(size_t)(col0 + r1s) * 256 + kn + ch1];
        }
        bf16x8 af[4], bfr[4];
#pragma unroll
        for (int mf = 0; mf < 4; ++mf)
            af[mf] = *(const bf16x8*)&As[(wm * 64 + mf * 16 + c) * 40 + g * 8];
#pragma unroll
        for (int nf = 0; nf < 4; ++nf)
            bfr[nf] = *(const bf16x8*)&Bs[(wn * 64 + nf * 16 + c) * 40 + g * 8];
#pragma unroll
        for (int mf = 0; mf < 4; ++mf)
#pragma unroll
            for (int nf = 0; nf < 4; ++nf)
                acc[mf][nf] = __builtin_amdgcn_mfma_f32_16x16x32_bf16(
                    af[mf], bfr[nf], acc[mf][nf], 0, 0, 0);
        __syncthreads();
    }
#pragma unroll
    for (int nf = 0; nf < 4; ++nf) {
        int col = col0 + wn * 64 + nf * 16 + c;
        float bz = bias[col];
#pragma unroll
        for (int mf = 0; mf < 4; ++mf)
#pragma unroll
            for (int r = 0; r < 4; ++r) {
                int row = row0 + wm * 64 + mf * 16 + g * 4 + r;
                C[(size_t)row * LDC + col] = f2bf((acc[mf][nf][r] + bz) * esc);
            }
    }
}

// ---------------- fused MFMA attention, compacted K/V, t-split 2-way ----------------
// grid 1024 = (bn, h, t-half). 8 waves; wave owns 32 t rows (2 t-frags).
// CAP=272 -> LDS 39.9KB -> 4 blocks/CU resident = exactly one full round.
template <bool MASKED>
__device__ __forceinline__ void attn_step(
    const short* K_lds, const short* Vt_lds, const bf16x8* qf,
    f32x4 (*ctxa)[2], f32x4* rsv, int l0, int clen, int g, int c) {
    bf16x8 ak = *(const bf16x8*)&K_lds[(l0 + c) * 40 + g * 8];
    bf16x4 vb0 = *(const bf16x4*)&Vt_lds[c * VS + l0 + g * 4];
    bf16x4 vb1 = *(const bf16x4*)&Vt_lds[(16 + c) * VS + l0 + g * 4];
    int lb = l0 + g * 4;
#pragma unroll
    for (int tf = 0; tf < 2; ++tf) {
        f32x4 s = __builtin_amdgcn_mfma_f32_16x16x32_bf16(
            ak, qf[tf], (f32x4){0.f, 0.f, 0.f, 0.f}, 0, 0, 0);
        float p0 = exp2f(s[0]);
        float p1 = exp2f(s[1]);
        float p2 = exp2f(s[2]);
        float p3 = exp2f(s[3]);
        if (MASKED) {
            p0 = (lb + 0 < clen) ? p0 : 0.f;
            p1 = (lb + 1 < clen) ? p1 : 0.f;
            p2 = (lb + 2 < clen) ? p2 : 0.f;
            p3 = (lb + 3 < clen) ? p3 : 0.f;
        }
        rsv[tf] += (f32x4){p0, p1, p2, p3};
        union { bf16x4 v; unsigned u[2]; } pu;
        pu.u[0] = pk2bf(p0, p1);
        pu.u[1] = pk2bf(p2, p3);
        __builtin_amdgcn_s_setprio(1);
        ctxa[tf][0] = mfma16(pu.v, vb0, ctxa[tf][0]);
        ctxa[tf][1] = mfma16(pu.v, vb1, ctxa[tf][1]);
        __builtin_amdgcn_s_setprio(0);
    }
}

__global__ __launch_bounds__(512, 8) void attn_kernel(
    const short* __restrict__ Q, const short* __restrict__ KV2,
    const int* __restrict__ cnt, short* __restrict__ ctx) {
    __shared__ __align__(16) short K_lds[CAP * 40];
    __shared__ __align__(16) short Vt_lds[32 * VS];
    int tid = threadIdx.x;
    int bx = blockIdx.x;
    int half = bx & 1, h = (bx >> 1) & 7, bn = bx >> 4, b = bn >> 3;
    int nv = cnt[bn];
    const short* kvr = KV2 + (size_t)bn * 512 * 512 + h * 32;

    int wid = tid >> 6, lane = tid & 63;
    int g = lane >> 4, c = lane & 15;
    int t0 = half * 256 + wid * 32;
    const short* qg = Q + ((size_t)b * 512 + t0 + c) * 256 + h * 32 + g * 8;
    bf16x8 qf[2];
#pragma unroll
    for (int tf = 0; tf < 2; ++tf)
        qf[tf] = *(const bf16x8*)&qg[(size_t)tf * 16 * 256];

    f32x4 ctxa[2][2];
    f32x4 rsv[2];
#pragma unroll
    for (int tf = 0; tf < 2; ++tf) {
        ctxa[tf][0] = (f32x4){0.f, 0.f, 0.f, 0.f};
        ctxa[tf][1] = (f32x4){0.f, 0.f, 0.f, 0.f};
        rsv[tf] = (f32x4){0.f, 0.f, 0.f, 0.f};
    }

    for (int base = 0; base < nv; base += CAP) {
        int rem = nv - base;
        int clen = rem < CAP ? rem : CAP;
        int clenp = (clen + 15) & ~15;
        if (base) __syncthreads();   // prior chunk fully consumed
        for (int idx = tid; idx < clenp * 4; idx += 512) {
            int i = idx >> 2, ch = idx & 3;
            bf16x8 kval = (bf16x8){0, 0, 0, 0, 0, 0, 0, 0};
            bf16x8 vval = (bf16x8){0, 0, 0, 0, 0, 0, 0, 0};
            if (i < clen) {
                size_t ro = (size_t)(base + i) * 512;
                kval = *(const bf16x8*)&kvr[ro + ch * 8];
                vval = *(const bf16x8*)&kvr[ro + 256 + ch * 8];
            }
            *(bf16x8*)&K_lds[i * 40 + ch * 8] = kval;
#pragma unroll
            for (int k = 0; k < 8; ++k)
                Vt_lds[(ch * 8 + k) * VS + i] = vval[k];
        }
        __syncthreads();
        int nfull = clen & ~15;
        for (int l0 = 0; l0 < nfull; l0 += 16)
            attn_step<false>(K_lds, Vt_lds, qf, ctxa, rsv, l0, clen, g, c);
        if (nfull < clenp)
            attn_step<true>(K_lds, Vt_lds, qf, ctxa, rsv, nfull, clen, g, c);
    }
#ifndef HAVE_MFMA16
    asm volatile("s_nop 7\ns_nop 7");
#endif
#pragma unroll
    for (int tf = 0; tf < 2; ++tf) {
        float r = (rsv[tf][0] + rsv[tf][1]) + (rsv[tf][2] + rsv[tf][3]);
        r += __shfl_xor(r, 16);
        r += __shfl_xor(r, 32);
        float inv = 1.f / r;   // rowsum for t-row = c, replicated over groups
#pragma unroll
        for (int rr = 0; rr < 4; ++rr) {
            float invr = __shfl(inv, (lane & 48) | (g * 4 + rr));
            ctxa[tf][0][rr] *= invr;
            ctxa[tf][1][rr] *= invr;
        }
    }
    __syncthreads();   // all waves done with K_lds/Vt_lds; reuse K_lds as staging
    // single-pass ctx write-back: 256 local rows via K_lds[0..256)
    int tl = wid * 32;
#pragma unroll
    for (int tf = 0; tf < 2; ++tf)
#pragma unroll
        for (int df = 0; df < 2; ++df)
#pragma unroll
            for (int rr = 0; rr < 4; ++rr)
                K_lds[(tl + tf * 16 + g * 4 + rr) * 40 + df * 16 + c] =
                    f2bf(ctxa[tf][df][rr]);
    __syncthreads();
    short* cg = ctx + (size_t)bn * 512 * 256 + h * 32 +
                (size_t)half * 256 * 256;
#pragma unroll
    for (int it = 0; it < 2; ++it) {
        int idx = tid + it * 512;
        int l = idx >> 2, ch = idx & 3;
        *(bf16x8*)&cg[(size_t)l * 256 + ch * 8] =
            *(const bf16x8*)&K_lds[l * 40 + ch * 8];
    }
}

// ---------------- fused Wo-GEMM + edge + mean_n (T14 async-STAGE split) ----------------
__global__ __launch_bounds__(256, 3) void wo_final(
    const short* __restrict__ ctx, const short* __restrict__ wo,
    const float* __restrict__ bo, const short* __restrict__ xpe,
    const float* __restrict__ nbr_edge, const float* __restrict__ Wedge,
    const float* __restrict__ bedge, float* __restrict__ out) {
    __shared__ __align__(16) short Ws[64 * 264];
    __shared__ __align__(16) short As[32 * 264];
    __shared__ __align__(16) float edge_s[8][36];
    int bx = blockIdx.x;
    int b = bx >> 6, tt = (bx >> 2) & 15, dt = bx & 3;
    int t0 = tt * 32, d0 = dt * 64;
    int tid = threadIdx.x;
    int wid = tid >> 6, lane = tid & 63;
    int th = wid & 1, dh = wid >> 1;
    int g = lane >> 4, c = lane & 15;

#pragma unroll
    for (int it = 0; it < 8; ++it) {
        int idx = tid + it * 256;
        int r = idx >> 5, kk = (idx & 31) * 8;
        *(bf16x8*)&Ws[r * 264 + kk] =
            *(const bf16x8*)&wo[(size_t)(d0 + r) * 256 + kk];
    }
    int trloc = th * 16 + g * 4;
    int dcol[2];
    float we[2][8], be[2], xb[2][4];
#pragma unroll
    for (int j = 0; j < 2; ++j) {
        dcol[j] = d0 + dh * 32 + j * 16 + c;
#pragma unroll
        for (int cc = 0; cc < 8; ++cc) we[j][cc] = Wedge[dcol[j] * 8 + cc];
        be[j] = bedge[dcol[j]];
        float boj = bo[dcol[j]];
#pragma unroll
        for (int r = 0; r < 4; ++r)
            xb[j][r] = bf2f(xpe[((size_t)b * 512 + t0 + trloc + r) * 256 +
                                dcol[j]]) + boj;
    }
    f32x4 oacc[2] = {(f32x4){0.f, 0.f, 0.f, 0.f}, (f32x4){0.f, 0.f, 0.f, 0.f}};

    int sr = tid >> 5, skk = (tid & 31) * 8;   // staging coords (4 rows/thread)
    int ec = tid >> 5, etl = tid & 31;         // edge coords
    // prologue: load n=0 into regs
    bf16x8 rv[4];
    float ev;
    {
        int bn = b * 8;
#pragma unroll
        for (int it = 0; it < 4; ++it)
            rv[it] = *(const bf16x8*)&ctx[((size_t)bn * 512 + t0 + sr + it * 8) *
                                          256 + skk];
        ev = nbr_edge[((size_t)bn * 8 + ec) * 512 + t0 + etl];
    }

    for (int n = 0; n < 8; ++n) {
        // write staged regs for this n
#pragma unroll
        for (int it = 0; it < 4; ++it)
            *(bf16x8*)&As[(sr + it * 8) * 264 + skk] = rv[it];
        edge_s[ec][etl] = ev;
        __syncthreads();
        // issue next n's loads (latency hides under MFMA below)
        if (n < 7) {
            int bn = b * 8 + n + 1;
#pragma unroll
            for (int it = 0; it < 4; ++it)
                rv[it] = *(const bf16x8*)&ctx[((size_t)bn * 512 + t0 + sr +
                                              it * 8) * 256 + skk];
            ev = nbr_edge[((size_t)bn * 8 + ec) * 512 + t0 + etl];
        }
        f32x4 acc[2] = {(f32x4){0.f, 0.f, 0.f, 0.f},
                        (f32x4){0.f, 0.f, 0.f, 0.f}};
#pragma unroll
        for (int k0 = 0; k0 < 8; ++k0) {
            bf16x8 af = *(const bf16x8*)&As[(th * 16 + c) * 264 + k0 * 32 + g * 8];
#pragma unroll
            for (int j = 0; j < 2; ++j) {
                bf16x8 bf = *(const bf16x8*)&Ws[(dh * 32 + j * 16 + c) * 264 +
                                                k0 * 32 + g * 8];
                acc[j] = __builtin_amdgcn_mfma_f32_16x16x32_bf16(af, bf, acc[j],
                                                                 0, 0, 0);
            }
        }
#pragma unroll
        for (int j = 0; j < 2; ++j)
#pragma unroll
            for (int r = 0; r < 4; ++r) {
                float e = be[j];
#pragma unroll
                for (int cc = 0; cc < 8; ++cc)
                    e = fmaf(edge_s[cc][trloc + r], we[j][cc], e);
                oacc[j][r] = fmaf(acc[j][r] + xb[j][r], e, oacc[j][r]);
            }
        __syncthreads();   // all reads of As/edge_s done before next write
    }
#pragma unroll
    for (int j = 0; j < 2; ++j)
#pragma unroll
        for (int r = 0; r < 4; ++r)
            out[((size_t)b * 512 + t0 + trloc + r) * 256 + dcol[j]] =
                oacc[j][r] * 0.125f;
}

extern "C" void kernel_launch(void* const* d_in, const int* in_sizes, int n_in,
                              void* d_out, int out_size, void* d_ws, size_t ws_size,
                              hipStream_t stream) {
    const float* x        = (const float*)d_in[0];
    const float* nbr_ts   = (const float*)d_in[1];
    const float* nbr_aux  = (const float*)d_in[2];
    const float* nbr_edge = (const float*)d_in[3];
    const int*   mask     = (const int*)d_in[4];
    const float* Wts  = (const float*)d_in[5];
    const float* bts  = (const float*)d_in[6];
    const float* Waux = (const float*)d_in[7];
    const float* baux = (const float*)d_in[8];
    const float* Wedge= (const float*)d_in[9];
    const float* bedge= (const float*)d_in[10];
    const float* ln_a = (const float*)d_in[11];
    const float* ln_b = (const float*)d_in[12];
    const float* Wq = (const float*)d_in[13];
    const float* bq = (const float*)d_in[14];
    const float* Wk = (const float*)d_in[15];
    const float* bk = (const float*)d_in[16];
    const float* Wv = (const float*)d_in[17];
    const float* bv = (const float*)d_in[18];
    const float* Wo = (const float*)d_in[19];
    const float* bo = (const float*)d_in[20];
    float* out = (float*)d_out;

    char* W = (char*)d_ws;
    float* pe_f    = (float*)(W);                 // 512 KB
    short* xpe_bf  = (short*)(W + 524288);        // 2 MB
    short* qin_bf  = (short*)(W + 4718592);       // 2 MB
    short* q_bf    = (short*)(W + 6815744);       // 2 MB
    short* kvc_bf  = (short*)(W + 8912896);       // 16 MB (compacted kv embed)
    short* kv2c_bf = (short*)(W + 25690112);      // 32 MB (compacted K|V, LDC 512)
    short* ctx_bf  = (short*)(W + 59244544);      // 16 MB
    short* w_bf    = (short*)(W + 92798976);      // 512 KB
    short* W2_bf   = (short*)(W + 93323264);      // 48 KB
    float* bias2_f = (float*)(W + 93372416);      // 1 KB
    float* bkv_f   = (float*)(W + 93373440);      // 2 KB
    int*   pos     = (int*)  (W + 93375488);      // 128 KB
    int*   cnt     = (int*)  (W + 93506560);      // 256 B
    short* wq_bf = w_bf;
    short* wkv_bf = w_bf + 65536;  // wk,wv contiguous => one [512][256] matrix
    short* wo_bf = w_bf + 196608;

    setup_kernel<<<2544, 512, 0, stream>>>(
        Wq, Wk, Wv, Wo, Wts, Waux, bts, baux, bk, bv, x, ln_a, ln_b, mask,
        w_bf, W2_bf, bias2_f, bkv_f, pe_f, pos, cnt, xpe_bf, qin_bf);
    kv_gemm<<<dim3(64, 4), 512, 0, stream>>>(nbr_ts, nbr_aux, W2_bf, bias2_f,
                                             pe_f, pos, kvc_bf);
    proj_gemm<<<1088, 256, 0, stream>>>(qin_bf, kvc_bf, wq_bf, wkv_bf, bq,
                                        bkv_f, cnt, q_bf, kv2c_bf);
    attn_kernel<<<1024, 512, 0, stream>>>(q_bf, kv2c_bf, cnt, ctx_bf);
    wo_final<<<512, 256, 0, stream>>>(ctx_bf, wo_bf, bo, xpe_bf, nbr_edge,
                                      Wedge, bedge, out);
}